// Round 5
// baseline (1664.494 us; speedup 1.0000x reference)
//
#include <hip/hip_runtime.h>
#include <math.h>

static constexpr int NN   = 20000;
static constexpr int TT   = 6;
static constexpr int EE   = 640000;
static constexpr int CINC = 3;
static constexpr int HH   = 64;

// ---- CSR build ----------------------------------------------------------
__global__ void count_kernel(const int* __restrict__ dst, int* __restrict__ cnt) {
    int e = blockIdx.x * blockDim.x + threadIdx.x;
    if (e < EE) atomicAdd(&cnt[dst[e]], 1);
}

__global__ void dinv_kernel(const int* __restrict__ cnt, float* __restrict__ dinv) {
    int i = blockIdx.x * blockDim.x + threadIdx.x;
    if (i < NN) dinv[i] = rsqrtf((float)cnt[i] + 1.0f);
}

// single block, 1024 threads: exclusive scan of cnt[0..NN) -> rowptr, cursor
__global__ void scan_kernel(const int* __restrict__ cnt, int* __restrict__ rowptr,
                            int* __restrict__ cursor) {
    __shared__ int part[1024];
    const int CHUNK = 20;  // 1024*20 = 20480 >= NN
    int tid = threadIdx.x;
    int base = tid * CHUNK;
    int local[CHUNK];
    int s = 0;
#pragma unroll
    for (int i = 0; i < CHUNK; ++i) {
        int idx = base + i;
        int v = (idx < NN) ? cnt[idx] : 0;
        local[i] = s;
        s += v;
    }
    part[tid] = s;
    __syncthreads();
    for (int off = 1; off < 1024; off <<= 1) {
        int v = part[tid];
        int add = (tid >= off) ? part[tid - off] : 0;
        __syncthreads();
        part[tid] = v + add;
        __syncthreads();
    }
    int ebase = (tid == 0) ? 0 : part[tid - 1];
#pragma unroll
    for (int i = 0; i < CHUNK; ++i) {
        int idx = base + i;
        if (idx < NN) {
            int v = ebase + local[i];
            rowptr[idx] = v;
            cursor[idx] = v;
        }
    }
    if (tid == 1023) rowptr[NN] = part[1023];
}

__global__ void fill_kernel(const int* __restrict__ src, const int* __restrict__ dst,
                            int* __restrict__ cursor, int* __restrict__ col) {
    int e = blockIdx.x * blockDim.x + threadIdx.x;
    if (e >= EE) return;
    int d = dst[e];
    int pos = atomicAdd(&cursor[d], 1);
    col[pos] = src[e];
}

// ---- GRU weight repack: A[k][jj] = {w_ir, w_iz, w_in, w_hr}, B[k][jj] = {w_hz, w_hn}
__global__ void pack_gru_kernel(const float* __restrict__ wih, const float* __restrict__ whh,
                                float* __restrict__ A, float* __restrict__ B) {
    int idx = blockIdx.x * blockDim.x + threadIdx.x;  // k*64 + jj
    if (idx >= HH * HH) return;
    int k = idx >> 6, jj = idx & 63;
    A[idx * 4 + 0] = wih[jj * HH + k];
    A[idx * 4 + 1] = wih[(64 + jj) * HH + k];
    A[idx * 4 + 2] = wih[(128 + jj) * HH + k];
    A[idx * 4 + 3] = whh[jj * HH + k];
    B[idx * 2 + 0] = whh[(64 + jj) * HH + k];
    B[idx * 2 + 1] = whh[(128 + jj) * HH + k];
}

// ---- GCN dense parts ----------------------------------------------------
// y = dinv * (x @ W1)   (x is [N,3])
__global__ void y1_kernel(const float* __restrict__ x, const float* __restrict__ W1,
                          const float* __restrict__ dinv, float* __restrict__ y) {
    int gid = blockIdx.x * blockDim.x + threadIdx.x;
    if (gid >= NN * HH) return;
    int node = gid >> 6, hh = gid & 63;
    const float* xr = x + node * CINC;
    float acc = 0.f;
#pragma unroll
    for (int k = 0; k < CINC; ++k) acc = fmaf(xr[k], W1[k * HH + hh], acc);
    y[gid] = dinv[node] * acc;
}

// y = dinv * (z @ W2)   (z is [N,64])
__global__ void y2_kernel(const float* __restrict__ z, const float* __restrict__ W2,
                          const float* __restrict__ dinv, float* __restrict__ y) {
    int gid = blockIdx.x * blockDim.x + threadIdx.x;
    if (gid >= NN * HH) return;
    int node = gid >> 6, hh = gid & 63;
    const float* zr = z + ((size_t)node << 6);
    float acc = 0.f;
#pragma unroll 8
    for (int k = 0; k < HH; ++k) acc = fmaf(zr[k], W2[k * HH + hh], acc);
    y[gid] = dinv[node] * acc;
}

// ---- CSR gather: z[n] = relu(dinv[n]*(sum_{s in N(n)} y[s] + y[n]) + b)
// one wave per node; 4 groups x 16 lanes; each group loads a whole 256B row
// (float4/lane), 4 neighbors in flight; butterfly-reduce across groups.
__global__ void gather_kernel(const int* __restrict__ rowptr, const int* __restrict__ col,
                              const float* __restrict__ dinv, const float* __restrict__ y,
                              const float* __restrict__ b, float* __restrict__ z) {
    int node = (blockIdx.x * blockDim.x + threadIdx.x) >> 6;
    if (node >= NN) return;
    int lane = threadIdx.x & 63;
    int g = lane >> 4, q = lane & 15;
    int pe = rowptr[node + 1];
    float4 acc = make_float4(0.f, 0.f, 0.f, 0.f);
    if (g == 0) acc = *(const float4*)(y + ((size_t)node << 6) + (q << 2));  // self
    for (int p = rowptr[node] + g; p < pe; p += 4) {
        int c = col[p];
        const float4 v = *(const float4*)(y + ((size_t)c << 6) + (q << 2));
        acc.x += v.x; acc.y += v.y; acc.z += v.z; acc.w += v.w;
    }
    // reduce the 4 groups (butterfly over lane bits 4,5)
    acc.x += __shfl_xor(acc.x, 16); acc.y += __shfl_xor(acc.y, 16);
    acc.z += __shfl_xor(acc.z, 16); acc.w += __shfl_xor(acc.w, 16);
    acc.x += __shfl_xor(acc.x, 32); acc.y += __shfl_xor(acc.y, 32);
    acc.z += __shfl_xor(acc.z, 32); acc.w += __shfl_xor(acc.w, 32);
    if (g == 0) {
        float d = dinv[node];
        const float4 bb = *(const float4*)(b + (q << 2));
        float4 o;
        o.x = fmaf(d, acc.x, bb.x); o.y = fmaf(d, acc.y, bb.y);
        o.z = fmaf(d, acc.z, bb.z); o.w = fmaf(d, acc.w, bb.w);
        o.x = o.x > 0.f ? o.x : 0.f; o.y = o.y > 0.f ? o.y : 0.f;
        o.z = o.z > 0.f ? o.z : 0.f; o.w = o.w > 0.f ? o.w : 0.f;
        *(float4*)(z + ((size_t)node << 6) + (q << 2)) = o;
    }
}

// ---- GRU cell (torch semantics), packed weights -------------------------
__global__ void gru_kernel(const float* __restrict__ z, const float* __restrict__ hin,
                           const float* __restrict__ A, const float* __restrict__ B,
                           const float* __restrict__ bih, const float* __restrict__ bhh,
                           float* __restrict__ hout) {
    int gid = blockIdx.x * blockDim.x + threadIdx.x;
    if (gid >= NN * HH) return;
    int node = gid >> 6, jj = gid & 63;
    const float* zr   = z   + ((size_t)node << 6);
    const float* hrow = hin + ((size_t)node << 6);
    const float4* A4 = (const float4*)A;
    const float2* B2 = (const float2*)B;
    float ir = 0, iz = 0, inn = 0, hr = 0, hz = 0, hn = 0;
#pragma unroll 4
    for (int k0 = 0; k0 < 16; ++k0) {
        const float4 zv = ((const float4*)zr)[k0];
        const float4 hv = ((const float4*)hrow)[k0];
        const float zk_[4] = {zv.x, zv.y, zv.z, zv.w};
        const float hk_[4] = {hv.x, hv.y, hv.z, hv.w};
#pragma unroll
        for (int u = 0; u < 4; ++u) {
            int k = k0 * 4 + u;
            const float4 a = A4[(k << 6) + jj];
            const float2 bb = B2[(k << 6) + jj];
            float zk = zk_[u], hk = hk_[u];
            ir  = fmaf(zk, a.x, ir);
            iz  = fmaf(zk, a.y, iz);
            inn = fmaf(zk, a.z, inn);
            hr  = fmaf(hk, a.w, hr);
            hz  = fmaf(hk, bb.x, hz);
            hn  = fmaf(hk, bb.y, hn);
        }
    }
    ir += bih[jj]; iz += bih[64 + jj]; inn += bih[128 + jj];
    hr += bhh[jj]; hz += bhh[64 + jj]; hn  += bhh[128 + jj];
    float r  = 1.f / (1.f + expf(-(ir + hr)));
    float zg = 1.f / (1.f + expf(-(iz + hz)));
    float ng = tanhf(inn + r * hn);
    hout[gid] = (1.f - zg) * ng + zg * hrow[jj];
}

// ---- MLP head -----------------------------------------------------------
__global__ void head1_kernel(const float* __restrict__ h, const float* __restrict__ W3,
                             const float* __restrict__ b3, float* __restrict__ hid) {
    int gid = blockIdx.x * blockDim.x + threadIdx.x;
    if (gid >= NN * HH) return;
    int node = gid >> 6, jj = gid & 63;
    const float* hrow = h + ((size_t)node << 6);
    float acc = b3[jj];
#pragma unroll 8
    for (int k = 0; k < HH; ++k) acc = fmaf(hrow[k], W3[k * HH + jj], acc);
    hid[gid] = acc > 0.f ? acc : 0.f;
}

__global__ void head2_kernel(const float* __restrict__ hid, const float* __restrict__ W4,
                             const float* __restrict__ b4, float* __restrict__ out) {
    int gid = blockIdx.x * blockDim.x + threadIdx.x;
    int node = gid >> 6;
    if (node >= NN) return;
    int lane = threadIdx.x & 63;
    float v = hid[((size_t)node << 6) + lane] * W4[lane];
    for (int off = 32; off; off >>= 1) v += __shfl_down(v, off);
    if (lane == 0) out[node] = 1.f / (1.f + expf(-(v + b4[0])));
}

extern "C" void kernel_launch(void* const* d_in, const int* in_sizes, int n_in,
                              void* d_out, int out_size, void* d_ws, size_t ws_size,
                              hipStream_t stream) {
    const float* nf    = (const float*)d_in[0];
    const int*   edges = (const int*)  d_in[1];
    const float* W1  = (const float*)d_in[2];
    const float* b1  = (const float*)d_in[3];
    const float* W2  = (const float*)d_in[4];
    const float* b2  = (const float*)d_in[5];
    const float* wih = (const float*)d_in[6];
    const float* whh = (const float*)d_in[7];
    const float* bih = (const float*)d_in[8];
    const float* bhh = (const float*)d_in[9];
    const float* W3  = (const float*)d_in[10];
    const float* b3  = (const float*)d_in[11];
    const float* W4  = (const float*)d_in[12];
    const float* b4  = (const float*)d_in[13];
    float* out = (float*)d_out;

    // workspace layout: ints first, then 16B-aligned floats
    int* wsi    = (int*)d_ws;
    int* cnt    = wsi;                 // NN
    int* rowptr = cnt + NN;            // NN+1
    int* cursor = rowptr + NN + 1;     // NN
    int* col    = cursor + NN;         // EE
    uintptr_t fbase = ((uintptr_t)(col + EE) + 15) & ~(uintptr_t)15;
    float* wsf  = (float*)fbase;
    float* packA = wsf;                      // 64*64*4
    float* packB = packA + HH * HH * 4;      // 64*64*2
    float* dinv = packB + HH * HH * 2;       // NN
    float* Y    = dinv + NN;                 // NN*HH
    float* Z    = Y + (size_t)NN * HH;       // NN*HH
    float* Hp   = Z + (size_t)NN * HH;       // NN*HH (h ping)
    float* Hq   = Hp + (size_t)NN * HH;      // NN*HH (h pong)

    const int BS  = 256;
    const int gNH = (NN * HH + BS - 1) / BS;
    const int gE  = (EE + BS - 1) / BS;
    const int gN  = (NN + BS - 1) / BS;

    hipMemsetAsync(Hp, 0, (size_t)NN * HH * sizeof(float), stream);
    pack_gru_kernel<<<(HH * HH + BS - 1) / BS, BS, 0, stream>>>(wih, whh, packA, packB);

    float* hin = Hp;
    float* hout = Hq;
    for (int t = 0; t < TT; ++t) {
        const int* src = edges + (size_t)t * 2 * EE;
        const int* dst = src + EE;
        const float* xt = nf + (size_t)t * NN * CINC;

        // CSR build (shared by both GCN layers)
        hipMemsetAsync(cnt, 0, NN * sizeof(int), stream);
        count_kernel<<<gE, BS, 0, stream>>>(dst, cnt);
        dinv_kernel<<<gN, BS, 0, stream>>>(cnt, dinv);
        scan_kernel<<<1, 1024, 0, stream>>>(cnt, rowptr, cursor);
        fill_kernel<<<gE, BS, 0, stream>>>(src, dst, cursor, col);

        // GCN layer 1
        y1_kernel<<<gNH, BS, 0, stream>>>(xt, W1, dinv, Y);
        gather_kernel<<<gNH, BS, 0, stream>>>(rowptr, col, dinv, Y, b1, Z);

        // GCN layer 2
        y2_kernel<<<gNH, BS, 0, stream>>>(Z, W2, dinv, Y);
        gather_kernel<<<gNH, BS, 0, stream>>>(rowptr, col, dinv, Y, b2, Z);

        // GRU
        gru_kernel<<<gNH, BS, 0, stream>>>(Z, hin, packA, packB, bih, bhh, hout);
        float* tmp = hin; hin = hout; hout = tmp;
    }

    head1_kernel<<<gNH, BS, 0, stream>>>(hin, W3, b3, Z);
    head2_kernel<<<gNH, BS, 0, stream>>>(Z, W4, b4, out);
}

// Round 6
// 1216.431 us; speedup vs baseline: 1.3683x; 1.3683x over previous
//
#include <hip/hip_runtime.h>
#include <math.h>

static constexpr int NN   = 20000;
static constexpr int TT   = 6;
static constexpr int EE   = 640000;
static constexpr int CINC = 3;
static constexpr int HH   = 64;
static constexpr int RB   = 8;   // nodes per wave in the dense kernels

// ---- CSR build ----------------------------------------------------------
__global__ void count_kernel(const int* __restrict__ dst, int* __restrict__ cnt) {
    int e = blockIdx.x * blockDim.x + threadIdx.x;
    if (e < EE) atomicAdd(&cnt[dst[e]], 1);
}

__global__ void dinv_kernel(const int* __restrict__ cnt, float* __restrict__ dinv) {
    int i = blockIdx.x * blockDim.x + threadIdx.x;
    if (i < NN) dinv[i] = rsqrtf((float)cnt[i] + 1.0f);
}

// single block, 1024 threads: exclusive scan of cnt[0..NN) -> rowptr, cursor
__global__ void scan_kernel(const int* __restrict__ cnt, int* __restrict__ rowptr,
                            int* __restrict__ cursor) {
    __shared__ int part[1024];
    const int CHUNK = 20;  // 1024*20 = 20480 >= NN
    int tid = threadIdx.x;
    int base = tid * CHUNK;
    int local[CHUNK];
    int s = 0;
#pragma unroll
    for (int i = 0; i < CHUNK; ++i) {
        int idx = base + i;
        int v = (idx < NN) ? cnt[idx] : 0;
        local[i] = s;
        s += v;
    }
    part[tid] = s;
    __syncthreads();
    for (int off = 1; off < 1024; off <<= 1) {
        int v = part[tid];
        int add = (tid >= off) ? part[tid - off] : 0;
        __syncthreads();
        part[tid] = v + add;
        __syncthreads();
    }
    int ebase = (tid == 0) ? 0 : part[tid - 1];
#pragma unroll
    for (int i = 0; i < CHUNK; ++i) {
        int idx = base + i;
        if (idx < NN) {
            int v = ebase + local[i];
            rowptr[idx] = v;
            cursor[idx] = v;
        }
    }
    if (tid == 1023) rowptr[NN] = part[1023];
}

__global__ void fill_kernel(const int* __restrict__ src, const int* __restrict__ dst,
                            int* __restrict__ cursor, int* __restrict__ col) {
    int e = blockIdx.x * blockDim.x + threadIdx.x;
    if (e >= EE) return;
    int d = dst[e];
    int pos = atomicAdd(&cursor[d], 1);
    col[pos] = src[e];
}

// ---- GRU weight repack: A[k][jj] = {w_ir, w_iz, w_in, w_hr}, B[k][jj] = {w_hz, w_hn}
__global__ void pack_gru_kernel(const float* __restrict__ wih, const float* __restrict__ whh,
                                float* __restrict__ A, float* __restrict__ B) {
    int idx = blockIdx.x * blockDim.x + threadIdx.x;  // k*64 + jj
    if (idx >= HH * HH) return;
    int k = idx >> 6, jj = idx & 63;
    A[idx * 4 + 0] = wih[jj * HH + k];
    A[idx * 4 + 1] = wih[(64 + jj) * HH + k];
    A[idx * 4 + 2] = wih[(128 + jj) * HH + k];
    A[idx * 4 + 3] = whh[jj * HH + k];
    B[idx * 2 + 0] = whh[(64 + jj) * HH + k];
    B[idx * 2 + 1] = whh[(128 + jj) * HH + k];
}

// ---- GCN dense parts ----------------------------------------------------
// y = dinv * (x @ W1)   (x is [N,3])
__global__ void y1_kernel(const float* __restrict__ x, const float* __restrict__ W1,
                          const float* __restrict__ dinv, float* __restrict__ y) {
    int gid = blockIdx.x * blockDim.x + threadIdx.x;
    if (gid >= NN * HH) return;
    int node = gid >> 6, hh = gid & 63;
    const float* xr = x + node * CINC;
    float acc = 0.f;
#pragma unroll
    for (int k = 0; k < CINC; ++k) acc = fmaf(xr[k], W1[k * HH + hh], acc);
    y[gid] = dinv[node] * acc;
}

// y = dinv * (z @ W2): one wave per RB nodes, lane = output feature
__global__ void y2_kernel(const float* __restrict__ z, const float* __restrict__ W2,
                          const float* __restrict__ dinv, float* __restrict__ y) {
    int nbase = blockIdx.x * RB;
    int lane = threadIdx.x;
    float acc[RB];
#pragma unroll
    for (int r = 0; r < RB; ++r) acc[r] = 0.f;
    for (int k0 = 0; k0 < 16; ++k0) {
        float4 zv[RB];
#pragma unroll
        for (int r = 0; r < RB; ++r)
            zv[r] = ((const float4*)(z + ((size_t)(nbase + r) << 6)))[k0];
#pragma unroll
        for (int u = 0; u < 4; ++u) {
            float w = W2[(k0 * 4 + u) * HH + lane];
#pragma unroll
            for (int r = 0; r < RB; ++r) {
                float zk = (u == 0) ? zv[r].x : (u == 1) ? zv[r].y : (u == 2) ? zv[r].z : zv[r].w;
                acc[r] = fmaf(zk, w, acc[r]);
            }
        }
    }
#pragma unroll
    for (int r = 0; r < RB; ++r)
        y[((size_t)(nbase + r) << 6) + lane] = dinv[nbase + r] * acc[r];
}

// ---- CSR gather: z[n] = relu(dinv[n]*(sum_{s in N(n)} y[s] + y[n]) + b)
// one wave per node; 4 groups x 16 lanes; each group loads a whole 256B row
__global__ void gather_kernel(const int* __restrict__ rowptr, const int* __restrict__ col,
                              const float* __restrict__ dinv, const float* __restrict__ y,
                              const float* __restrict__ b, float* __restrict__ z) {
    int node = (blockIdx.x * blockDim.x + threadIdx.x) >> 6;
    if (node >= NN) return;
    int lane = threadIdx.x & 63;
    int g = lane >> 4, q = lane & 15;
    int pe = rowptr[node + 1];
    float4 acc = make_float4(0.f, 0.f, 0.f, 0.f);
    if (g == 0) acc = *(const float4*)(y + ((size_t)node << 6) + (q << 2));  // self
    for (int p = rowptr[node] + g; p < pe; p += 4) {
        int c = col[p];
        const float4 v = *(const float4*)(y + ((size_t)c << 6) + (q << 2));
        acc.x += v.x; acc.y += v.y; acc.z += v.z; acc.w += v.w;
    }
    acc.x += __shfl_xor(acc.x, 16); acc.y += __shfl_xor(acc.y, 16);
    acc.z += __shfl_xor(acc.z, 16); acc.w += __shfl_xor(acc.w, 16);
    acc.x += __shfl_xor(acc.x, 32); acc.y += __shfl_xor(acc.y, 32);
    acc.z += __shfl_xor(acc.z, 32); acc.w += __shfl_xor(acc.w, 32);
    if (g == 0) {
        float d = dinv[node];
        const float4 bb = *(const float4*)(b + (q << 2));
        float4 o;
        o.x = fmaf(d, acc.x, bb.x); o.y = fmaf(d, acc.y, bb.y);
        o.z = fmaf(d, acc.z, bb.z); o.w = fmaf(d, acc.w, bb.w);
        o.x = o.x > 0.f ? o.x : 0.f; o.y = o.y > 0.f ? o.y : 0.f;
        o.z = o.z > 0.f ? o.z : 0.f; o.w = o.w > 0.f ? o.w : 0.f;
        *(float4*)(z + ((size_t)node << 6) + (q << 2)) = o;
    }
}

// ---- GRU cell: one wave per RB nodes, lane = output feature jj ----------
__global__ void gru_kernel(const float* __restrict__ z, const float* __restrict__ hin,
                           const float* __restrict__ A, const float* __restrict__ B,
                           const float* __restrict__ bih, const float* __restrict__ bhh,
                           float* __restrict__ hout) {
    int nbase = blockIdx.x * RB;
    int lane = threadIdx.x;  // jj
    const float4* A4 = (const float4*)A;
    const float2* B2 = (const float2*)B;
    float ir[RB], iz[RB], in_[RB], hr[RB], hz[RB], hn[RB];
#pragma unroll
    for (int r = 0; r < RB; ++r) { ir[r] = iz[r] = in_[r] = hr[r] = hz[r] = hn[r] = 0.f; }
    for (int k0 = 0; k0 < 16; ++k0) {
        float4 zv[RB], hv[RB];
#pragma unroll
        for (int r = 0; r < RB; ++r) {
            zv[r] = ((const float4*)(z   + ((size_t)(nbase + r) << 6)))[k0];
            hv[r] = ((const float4*)(hin + ((size_t)(nbase + r) << 6)))[k0];
        }
#pragma unroll
        for (int u = 0; u < 4; ++u) {
            int k = k0 * 4 + u;
            float4 a  = A4[(k << 6) + lane];
            float2 b2 = B2[(k << 6) + lane];
#pragma unroll
            for (int r = 0; r < RB; ++r) {
                float zk = (u == 0) ? zv[r].x : (u == 1) ? zv[r].y : (u == 2) ? zv[r].z : zv[r].w;
                float hk = (u == 0) ? hv[r].x : (u == 1) ? hv[r].y : (u == 2) ? hv[r].z : hv[r].w;
                ir[r]  = fmaf(zk, a.x,  ir[r]);
                iz[r]  = fmaf(zk, a.y,  iz[r]);
                in_[r] = fmaf(zk, a.z,  in_[r]);
                hr[r]  = fmaf(hk, a.w,  hr[r]);
                hz[r]  = fmaf(hk, b2.x, hz[r]);
                hn[r]  = fmaf(hk, b2.y, hn[r]);
            }
        }
    }
    float bi0 = bih[lane], bi1 = bih[64 + lane], bi2 = bih[128 + lane];
    float bh0 = bhh[lane], bh1 = bhh[64 + lane], bh2 = bhh[128 + lane];
#pragma unroll
    for (int r = 0; r < RB; ++r) {
        float rr = 1.f / (1.f + expf(-(ir[r] + bi0 + hr[r] + bh0)));
        float zg = 1.f / (1.f + expf(-(iz[r] + bi1 + hz[r] + bh1)));
        float ng = tanhf(in_[r] + bi2 + rr * (hn[r] + bh2));
        float hprev = hin[((size_t)(nbase + r) << 6) + lane];
        hout[((size_t)(nbase + r) << 6) + lane] = (1.f - zg) * ng + zg * hprev;
    }
}

// ---- MLP head -----------------------------------------------------------
// hid = relu(h @ W3 + b3): one wave per RB nodes
__global__ void head1_kernel(const float* __restrict__ h, const float* __restrict__ W3,
                             const float* __restrict__ b3, float* __restrict__ hid) {
    int nbase = blockIdx.x * RB;
    int lane = threadIdx.x;
    float acc[RB];
#pragma unroll
    for (int r = 0; r < RB; ++r) acc[r] = 0.f;
    for (int k0 = 0; k0 < 16; ++k0) {
        float4 hv[RB];
#pragma unroll
        for (int r = 0; r < RB; ++r)
            hv[r] = ((const float4*)(h + ((size_t)(nbase + r) << 6)))[k0];
#pragma unroll
        for (int u = 0; u < 4; ++u) {
            float w = W3[(k0 * 4 + u) * HH + lane];
#pragma unroll
            for (int r = 0; r < RB; ++r) {
                float hk = (u == 0) ? hv[r].x : (u == 1) ? hv[r].y : (u == 2) ? hv[r].z : hv[r].w;
                acc[r] = fmaf(hk, w, acc[r]);
            }
        }
    }
    float bb = b3[lane];
#pragma unroll
    for (int r = 0; r < RB; ++r) {
        float v = acc[r] + bb;
        hid[((size_t)(nbase + r) << 6) + lane] = v > 0.f ? v : 0.f;
    }
}

__global__ void head2_kernel(const float* __restrict__ hid, const float* __restrict__ W4,
                             const float* __restrict__ b4, float* __restrict__ out) {
    int gid = blockIdx.x * blockDim.x + threadIdx.x;
    int node = gid >> 6;
    if (node >= NN) return;
    int lane = threadIdx.x & 63;
    float v = hid[((size_t)node << 6) + lane] * W4[lane];
    for (int off = 32; off; off >>= 1) v += __shfl_down(v, off);
    if (lane == 0) out[node] = 1.f / (1.f + expf(-(v + b4[0])));
}

extern "C" void kernel_launch(void* const* d_in, const int* in_sizes, int n_in,
                              void* d_out, int out_size, void* d_ws, size_t ws_size,
                              hipStream_t stream) {
    const float* nf    = (const float*)d_in[0];
    const int*   edges = (const int*)  d_in[1];
    const float* W1  = (const float*)d_in[2];
    const float* b1  = (const float*)d_in[3];
    const float* W2  = (const float*)d_in[4];
    const float* b2  = (const float*)d_in[5];
    const float* wih = (const float*)d_in[6];
    const float* whh = (const float*)d_in[7];
    const float* bih = (const float*)d_in[8];
    const float* bhh = (const float*)d_in[9];
    const float* W3  = (const float*)d_in[10];
    const float* b3  = (const float*)d_in[11];
    const float* W4  = (const float*)d_in[12];
    const float* b4  = (const float*)d_in[13];
    float* out = (float*)d_out;

    // workspace layout: ints first, then 16B-aligned floats
    int* wsi    = (int*)d_ws;
    int* cnt    = wsi;                 // NN
    int* rowptr = cnt + NN;            // NN+1
    int* cursor = rowptr + NN + 1;     // NN
    int* col    = cursor + NN;         // EE
    uintptr_t fbase = ((uintptr_t)(col + EE) + 15) & ~(uintptr_t)15;
    float* wsf  = (float*)fbase;
    float* packA = wsf;                      // 64*64*4
    float* packB = packA + HH * HH * 4;      // 64*64*2
    float* dinv = packB + HH * HH * 2;       // NN
    float* Y    = dinv + NN;                 // NN*HH
    float* Z    = Y + (size_t)NN * HH;       // NN*HH
    float* Hp   = Z + (size_t)NN * HH;       // NN*HH (h ping)
    float* Hq   = Hp + (size_t)NN * HH;      // NN*HH (h pong)

    const int BS  = 256;
    const int gNH = (NN * HH + BS - 1) / BS;
    const int gE  = (EE + BS - 1) / BS;
    const int gN  = (NN + BS - 1) / BS;
    const int gRB = NN / RB;  // 2500 waves, one per block of 64

    hipMemsetAsync(Hp, 0, (size_t)NN * HH * sizeof(float), stream);
    pack_gru_kernel<<<(HH * HH + BS - 1) / BS, BS, 0, stream>>>(wih, whh, packA, packB);

    float* hin = Hp;
    float* hout = Hq;
    for (int t = 0; t < TT; ++t) {
        const int* src = edges + (size_t)t * 2 * EE;
        const int* dst = src + EE;
        const float* xt = nf + (size_t)t * NN * CINC;

        // CSR build (shared by both GCN layers)
        hipMemsetAsync(cnt, 0, NN * sizeof(int), stream);
        count_kernel<<<gE, BS, 0, stream>>>(dst, cnt);
        dinv_kernel<<<gN, BS, 0, stream>>>(cnt, dinv);
        scan_kernel<<<1, 1024, 0, stream>>>(cnt, rowptr, cursor);
        fill_kernel<<<gE, BS, 0, stream>>>(src, dst, cursor, col);

        // GCN layer 1
        y1_kernel<<<gNH, BS, 0, stream>>>(xt, W1, dinv, Y);
        gather_kernel<<<gNH, BS, 0, stream>>>(rowptr, col, dinv, Y, b1, Z);

        // GCN layer 2
        y2_kernel<<<gRB, 64, 0, stream>>>(Z, W2, dinv, Y);
        gather_kernel<<<gNH, BS, 0, stream>>>(rowptr, col, dinv, Y, b2, Z);

        // GRU
        gru_kernel<<<gRB, 64, 0, stream>>>(Z, hin, packA, packB, bih, bhh, hout);
        float* tmp = hin; hin = hout; hout = tmp;
    }

    head1_kernel<<<gRB, 64, 0, stream>>>(hin, W3, b3, Z);
    head2_kernel<<<gNH, BS, 0, stream>>>(Z, W4, b4, out);
}

// Round 7
// 973.168 us; speedup vs baseline: 1.7104x; 1.2500x over previous
//
#include <hip/hip_runtime.h>
#include <math.h>

static constexpr int NN   = 20000;
static constexpr int TT   = 6;
static constexpr int EE   = 640000;
static constexpr int CINC = 3;
static constexpr int HH   = 64;
static constexpr int RB   = 8;   // nodes per wave in the dense kernels

// ---- bf16 helpers (storage = ushort) ------------------------------------
__device__ inline unsigned short f2bf(float f) {
    unsigned u = __float_as_uint(f);
    unsigned r = (u + 0x7FFFu + ((u >> 16) & 1u)) >> 16;  // RTNE
    return (unsigned short)r;
}
__device__ inline float bflo(unsigned u) { return __uint_as_float(u << 16); }
__device__ inline float bfhi(unsigned u) { return __uint_as_float(u & 0xFFFF0000u); }

// ---- batched CSR build over all 6 timesteps ------------------------------
__global__ void count6_kernel(const int* __restrict__ edges, int* __restrict__ cnt6) {
    int t = blockIdx.y;
    int e = blockIdx.x * blockDim.x + threadIdx.x;
    if (e < EE) {
        const int* dst = edges + (size_t)t * 2 * EE + EE;
        atomicAdd(&cnt6[t * NN + dst[e]], 1);
    }
}

// 6 blocks (one per t), 1024 threads: exclusive scan + dinv
__global__ void scan6_kernel(const int* __restrict__ cnt6, int* __restrict__ rowptr6,
                             int* __restrict__ cursor6, float* __restrict__ dinv6) {
    int t = blockIdx.x;
    const int* cnt = cnt6 + t * NN;
    int* rowptr = rowptr6 + t * (NN + 1);
    int* cursor = cursor6 + t * NN;
    float* dinv = dinv6 + t * NN;
    __shared__ int part[1024];
    const int CHUNK = 20;  // 1024*20 >= NN
    int tid = threadIdx.x;
    int base = tid * CHUNK;
    int local[CHUNK];
    int s = 0;
#pragma unroll
    for (int i = 0; i < CHUNK; ++i) {
        int idx = base + i;
        int v = (idx < NN) ? cnt[idx] : 0;
        local[i] = s;
        s += v;
    }
    part[tid] = s;
    __syncthreads();
    for (int off = 1; off < 1024; off <<= 1) {
        int v = part[tid];
        int add = (tid >= off) ? part[tid - off] : 0;
        __syncthreads();
        part[tid] = v + add;
        __syncthreads();
    }
    int ebase = (tid == 0) ? 0 : part[tid - 1];
#pragma unroll
    for (int i = 0; i < CHUNK; ++i) {
        int idx = base + i;
        if (idx < NN) {
            int v = ebase + local[i];
            rowptr[idx] = v;
            cursor[idx] = v;
            dinv[idx] = rsqrtf((float)cnt[idx] + 1.0f);
        }
    }
    if (tid == 1023) rowptr[NN] = part[1023];
}

__global__ void fill6_kernel(const int* __restrict__ edges, int* __restrict__ cursor6,
                             int* __restrict__ col6) {
    int t = blockIdx.y;
    int e = blockIdx.x * blockDim.x + threadIdx.x;
    if (e >= EE) return;
    const int* src = edges + (size_t)t * 2 * EE;
    const int* dst = src + EE;
    int d = dst[e];
    int pos = atomicAdd(&cursor6[t * NN + d], 1);
    col6[(size_t)t * EE + pos] = src[e];
}

// ---- GRU weight repack: A[k][jj] = {w_ir,w_iz,w_in,w_hr}, B[k][jj] = {w_hz,w_hn}
__global__ void pack_gru_kernel(const float* __restrict__ wih, const float* __restrict__ whh,
                                float* __restrict__ A, float* __restrict__ B) {
    int idx = blockIdx.x * blockDim.x + threadIdx.x;  // k*64 + jj
    if (idx >= HH * HH) return;
    int k = idx >> 6, jj = idx & 63;
    A[idx * 4 + 0] = wih[jj * HH + k];
    A[idx * 4 + 1] = wih[(64 + jj) * HH + k];
    A[idx * 4 + 2] = wih[(128 + jj) * HH + k];
    A[idx * 4 + 3] = whh[jj * HH + k];
    B[idx * 2 + 0] = whh[(64 + jj) * HH + k];
    B[idx * 2 + 1] = whh[(128 + jj) * HH + k];
}

// ---- y1 for ALL t: y = dinv * (x @ W1), bf16 out ------------------------
__global__ void y1all_kernel(const float* __restrict__ nf, const float* __restrict__ W1,
                             const float* __restrict__ dinv6, unsigned short* __restrict__ Yb) {
    int t = blockIdx.y;
    int gid = blockIdx.x * blockDim.x + threadIdx.x;
    if (gid >= NN * HH) return;
    int node = gid >> 6, hh = gid & 63;
    const float* xr = nf + (size_t)t * NN * CINC + node * CINC;
    float acc = 0.f;
#pragma unroll
    for (int k = 0; k < CINC; ++k) acc = fmaf(xr[k], W1[k * HH + hh], acc);
    Yb[(size_t)t * NN * HH + gid] = f2bf(dinv6[t * NN + node] * acc);
}

// ---- y2: y = dinv * (z @ W2), one wave per RB nodes, bf16 out -----------
__global__ void y2_kernel(const float* __restrict__ z, const float* __restrict__ W2,
                          const float* __restrict__ dinv, unsigned short* __restrict__ y) {
    int nbase = blockIdx.x * RB;
    int lane = threadIdx.x;
    float acc[RB];
#pragma unroll
    for (int r = 0; r < RB; ++r) acc[r] = 0.f;
    for (int k0 = 0; k0 < 16; ++k0) {
        float4 zv[RB];
#pragma unroll
        for (int r = 0; r < RB; ++r)
            zv[r] = ((const float4*)(z + ((size_t)(nbase + r) << 6)))[k0];
#pragma unroll
        for (int u = 0; u < 4; ++u) {
            float w = W2[(k0 * 4 + u) * HH + lane];
#pragma unroll
            for (int r = 0; r < RB; ++r) {
                float zk = (u == 0) ? zv[r].x : (u == 1) ? zv[r].y : (u == 2) ? zv[r].z : zv[r].w;
                acc[r] = fmaf(zk, w, acc[r]);
            }
        }
    }
#pragma unroll
    for (int r = 0; r < RB; ++r)
        y[((size_t)(nbase + r) << 6) + lane] = f2bf(dinv[nbase + r] * acc[r]);
}

// ---- CSR gather (bf16 rows): z[n] = relu(dinv[n]*(sum y[s] + y[n]) + b)
// one wave per node; 8 groups x 8 lanes; each group loads a 128B bf16 row
__global__ void gather_kernel(const int* __restrict__ rowptr, const int* __restrict__ col,
                              const float* __restrict__ dinv, const unsigned short* __restrict__ y,
                              const float* __restrict__ b, float* __restrict__ z) {
    int node = (blockIdx.x * blockDim.x + threadIdx.x) >> 6;
    if (node >= NN) return;
    int lane = threadIdx.x & 63;
    int g = lane >> 3, q = lane & 7;
    int ps = rowptr[node], pe = rowptr[node + 1];
    float acc[8];
    if (g == 0) {  // self term
        const uint4 v = *(const uint4*)(y + ((size_t)node << 6) + (q << 3));
        acc[0] = bflo(v.x); acc[1] = bfhi(v.x);
        acc[2] = bflo(v.y); acc[3] = bfhi(v.y);
        acc[4] = bflo(v.z); acc[5] = bfhi(v.z);
        acc[6] = bflo(v.w); acc[7] = bfhi(v.w);
    } else {
#pragma unroll
        for (int j = 0; j < 8; ++j) acc[j] = 0.f;
    }
    for (int p = ps + g; p < pe; p += 8) {
        int c = col[p];
        const uint4 v = *(const uint4*)(y + ((size_t)c << 6) + (q << 3));
        acc[0] += bflo(v.x); acc[1] += bfhi(v.x);
        acc[2] += bflo(v.y); acc[3] += bfhi(v.y);
        acc[4] += bflo(v.z); acc[5] += bfhi(v.z);
        acc[6] += bflo(v.w); acc[7] += bfhi(v.w);
    }
    // butterfly-reduce the 8 groups (lane bits 3,4,5)
#pragma unroll
    for (int j = 0; j < 8; ++j) {
        acc[j] += __shfl_xor(acc[j], 8);
        acc[j] += __shfl_xor(acc[j], 16);
        acc[j] += __shfl_xor(acc[j], 32);
    }
    if (g == 0) {
        float d = dinv[node];
        const float4 b0 = *(const float4*)(b + (q << 3));
        const float4 b1 = *(const float4*)(b + (q << 3) + 4);
        float4 o0, o1;
        o0.x = fmaf(d, acc[0], b0.x); o0.y = fmaf(d, acc[1], b0.y);
        o0.z = fmaf(d, acc[2], b0.z); o0.w = fmaf(d, acc[3], b0.w);
        o1.x = fmaf(d, acc[4], b1.x); o1.y = fmaf(d, acc[5], b1.y);
        o1.z = fmaf(d, acc[6], b1.z); o1.w = fmaf(d, acc[7], b1.w);
        o0.x = o0.x > 0.f ? o0.x : 0.f; o0.y = o0.y > 0.f ? o0.y : 0.f;
        o0.z = o0.z > 0.f ? o0.z : 0.f; o0.w = o0.w > 0.f ? o0.w : 0.f;
        o1.x = o1.x > 0.f ? o1.x : 0.f; o1.y = o1.y > 0.f ? o1.y : 0.f;
        o1.z = o1.z > 0.f ? o1.z : 0.f; o1.w = o1.w > 0.f ? o1.w : 0.f;
        float* zr = z + ((size_t)node << 6) + (q << 3);
        *(float4*)zr = o0;
        *(float4*)(zr + 4) = o1;
    }
}

// ---- GRU cell: one wave per RB nodes, lane = output feature jj ----------
__global__ void gru_kernel(const float* __restrict__ z, const float* __restrict__ hin,
                           const float* __restrict__ A, const float* __restrict__ B,
                           const float* __restrict__ bih, const float* __restrict__ bhh,
                           float* __restrict__ hout) {
    int nbase = blockIdx.x * RB;
    int lane = threadIdx.x;  // jj
    const float4* A4 = (const float4*)A;
    const float2* B2 = (const float2*)B;
    float ir[RB], iz[RB], in_[RB], hr[RB], hz[RB], hn[RB];
#pragma unroll
    for (int r = 0; r < RB; ++r) { ir[r] = iz[r] = in_[r] = hr[r] = hz[r] = hn[r] = 0.f; }
    for (int k0 = 0; k0 < 16; ++k0) {
        float4 zv[RB], hv[RB];
#pragma unroll
        for (int r = 0; r < RB; ++r) {
            zv[r] = ((const float4*)(z   + ((size_t)(nbase + r) << 6)))[k0];
            hv[r] = ((const float4*)(hin + ((size_t)(nbase + r) << 6)))[k0];
        }
#pragma unroll
        for (int u = 0; u < 4; ++u) {
            int k = k0 * 4 + u;
            float4 a  = A4[(k << 6) + lane];
            float2 b2 = B2[(k << 6) + lane];
#pragma unroll
            for (int r = 0; r < RB; ++r) {
                float zk = (u == 0) ? zv[r].x : (u == 1) ? zv[r].y : (u == 2) ? zv[r].z : zv[r].w;
                float hk = (u == 0) ? hv[r].x : (u == 1) ? hv[r].y : (u == 2) ? hv[r].z : hv[r].w;
                ir[r]  = fmaf(zk, a.x,  ir[r]);
                iz[r]  = fmaf(zk, a.y,  iz[r]);
                in_[r] = fmaf(zk, a.z,  in_[r]);
                hr[r]  = fmaf(hk, a.w,  hr[r]);
                hz[r]  = fmaf(hk, b2.x, hz[r]);
                hn[r]  = fmaf(hk, b2.y, hn[r]);
            }
        }
    }
    float bi0 = bih[lane], bi1 = bih[64 + lane], bi2 = bih[128 + lane];
    float bh0 = bhh[lane], bh1 = bhh[64 + lane], bh2 = bhh[128 + lane];
#pragma unroll
    for (int r = 0; r < RB; ++r) {
        float rr = 1.f / (1.f + expf(-(ir[r] + bi0 + hr[r] + bh0)));
        float zg = 1.f / (1.f + expf(-(iz[r] + bi1 + hz[r] + bh1)));
        float ng = tanhf(in_[r] + bi2 + rr * (hn[r] + bh2));
        float hprev = hin[((size_t)(nbase + r) << 6) + lane];
        hout[((size_t)(nbase + r) << 6) + lane] = (1.f - zg) * ng + zg * hprev;
    }
}

// ---- fused MLP head: out = sigmoid(relu(h@W3+b3)@W4 + b4) ---------------
__global__ void head_kernel(const float* __restrict__ h, const float* __restrict__ W3,
                            const float* __restrict__ b3, const float* __restrict__ W4,
                            const float* __restrict__ b4, float* __restrict__ out) {
    int nbase = blockIdx.x * RB;
    int lane = threadIdx.x;
    float acc[RB];
#pragma unroll
    for (int r = 0; r < RB; ++r) acc[r] = 0.f;
    for (int k0 = 0; k0 < 16; ++k0) {
        float4 hv[RB];
#pragma unroll
        for (int r = 0; r < RB; ++r)
            hv[r] = ((const float4*)(h + ((size_t)(nbase + r) << 6)))[k0];
#pragma unroll
        for (int u = 0; u < 4; ++u) {
            float w = W3[(k0 * 4 + u) * HH + lane];
#pragma unroll
            for (int r = 0; r < RB; ++r) {
                float hk = (u == 0) ? hv[r].x : (u == 1) ? hv[r].y : (u == 2) ? hv[r].z : hv[r].w;
                acc[r] = fmaf(hk, w, acc[r]);
            }
        }
    }
    float bb = b3[lane], w4 = W4[lane], b40 = b4[0];
#pragma unroll
    for (int r = 0; r < RB; ++r) {
        float v = acc[r] + bb;
        v = v > 0.f ? v : 0.f;
        float s = v * w4;
        s += __shfl_xor(s, 32); s += __shfl_xor(s, 16); s += __shfl_xor(s, 8);
        s += __shfl_xor(s, 4);  s += __shfl_xor(s, 2);  s += __shfl_xor(s, 1);
        if (lane == r) out[nbase + r] = 1.f / (1.f + expf(-(s + b40)));
    }
}

extern "C" void kernel_launch(void* const* d_in, const int* in_sizes, int n_in,
                              void* d_out, int out_size, void* d_ws, size_t ws_size,
                              hipStream_t stream) {
    const float* nf    = (const float*)d_in[0];
    const int*   edges = (const int*)  d_in[1];
    const float* W1  = (const float*)d_in[2];
    const float* b1  = (const float*)d_in[3];
    const float* W2  = (const float*)d_in[4];
    const float* b2  = (const float*)d_in[5];
    const float* wih = (const float*)d_in[6];
    const float* whh = (const float*)d_in[7];
    const float* bih = (const float*)d_in[8];
    const float* bhh = (const float*)d_in[9];
    const float* W3  = (const float*)d_in[10];
    const float* b3  = (const float*)d_in[11];
    const float* W4  = (const float*)d_in[12];
    const float* b4  = (const float*)d_in[13];
    float* out = (float*)d_out;

    // workspace: int arrays (16B-size-aligned ones first), then floats, then bf16
    int* wsi     = (int*)d_ws;
    int* cnt6    = wsi;                      // 6*NN
    int* cursor6 = cnt6 + 6 * NN;            // 6*NN
    int* col6    = cursor6 + 6 * NN;         // 6*EE
    int* rowptr6 = col6 + (size_t)6 * EE;    // 6*(NN+1)
    uintptr_t fbase = ((uintptr_t)(rowptr6 + 6 * (NN + 1)) + 15) & ~(uintptr_t)15;
    float* packA = (float*)fbase;            // 64*64*4
    float* packB = packA + HH * HH * 4;      // 64*64*2
    float* dinv6 = packB + HH * HH * 2;      // 6*NN
    float* Z     = dinv6 + 6 * NN;           // NN*HH
    float* Hp    = Z + (size_t)NN * HH;      // NN*HH (h ping)
    float* Hq    = Hp + (size_t)NN * HH;     // NN*HH (h pong)
    unsigned short* Yb = (unsigned short*)(Hq + (size_t)NN * HH);  // 6*NN*HH bf16
    unsigned short* Y2 = Yb + (size_t)6 * NN * HH;                 // NN*HH bf16

    const int BS  = 256;
    const int gNH = (NN * HH + BS - 1) / BS;   // 5000
    const int gE  = (EE + BS - 1) / BS;        // 2500
    const int gRB = NN / RB;                   // 2500

    hipMemsetAsync(cnt6, 0, 6 * NN * sizeof(int), stream);
    hipMemsetAsync(Hp, 0, (size_t)NN * HH * sizeof(float), stream);
    pack_gru_kernel<<<(HH * HH + BS - 1) / BS, BS, 0, stream>>>(wih, whh, packA, packB);

    count6_kernel<<<dim3(gE, TT), BS, 0, stream>>>(edges, cnt6);
    scan6_kernel<<<TT, 1024, 0, stream>>>(cnt6, rowptr6, cursor6, dinv6);
    fill6_kernel<<<dim3(gE, TT), BS, 0, stream>>>(edges, cursor6, col6);
    y1all_kernel<<<dim3(gNH, TT), BS, 0, stream>>>(nf, W1, dinv6, Yb);

    float* hin = Hp;
    float* hout = Hq;
    for (int t = 0; t < TT; ++t) {
        const int* rp = rowptr6 + t * (NN + 1);
        const int* cl = col6 + (size_t)t * EE;
        const float* dv = dinv6 + t * NN;

        gather_kernel<<<gNH, BS, 0, stream>>>(rp, cl, dv, Yb + (size_t)t * NN * HH, b1, Z);
        y2_kernel<<<gRB, 64, 0, stream>>>(Z, W2, dv, Y2);
        gather_kernel<<<gNH, BS, 0, stream>>>(rp, cl, dv, Y2, b2, Z);
        gru_kernel<<<gRB, 64, 0, stream>>>(Z, hin, packA, packB, bih, bhh, hout);
        float* tmp = hin; hin = hout; hout = tmp;
    }

    head_kernel<<<gRB, 64, 0, stream>>>(hin, W3, b3, W4, b4, out);
}

// Round 9
// 728.656 us; speedup vs baseline: 2.2843x; 1.3356x over previous
//
#include <hip/hip_runtime.h>
#include <math.h>

static constexpr int NN   = 20000;
static constexpr int TT   = 6;
static constexpr int EE   = 640000;
static constexpr int CINC = 3;
static constexpr int HH   = 64;
static constexpr int RB   = 8;    // nodes per wave in the dense kernels
static constexpr int BKSH = 7;    // 128 nodes per bucket
static constexpr int NBKT = (NN + (1 << BKSH) - 1) >> BKSH;  // 157
static constexpr int CAP  = 6144; // bucket capacity (expected 4096, +32 sigma)
static constexpr int EPB  = 4096; // edges per workgroup in bin phase

// ---- bf16 helpers (storage = ushort) ------------------------------------
__device__ inline unsigned short f2bf(float f) {
    unsigned u = __float_as_uint(f);
    unsigned r = (u + 0x7FFFu + ((u >> 16) & 1u)) >> 16;  // RTNE
    return (unsigned short)r;
}
__device__ inline float bflo(unsigned u) { return __uint_as_float(u << 16); }
__device__ inline float bfhi(unsigned u) { return __uint_as_float(u & 0xFFFF0000u); }

// ---- batched degree count over all 6 timesteps ---------------------------
__global__ void count6_kernel(const int* __restrict__ edges, int* __restrict__ cnt6) {
    int t = blockIdx.y;
    int e = blockIdx.x * blockDim.x + threadIdx.x;
    if (e < EE) {
        const int* dst = edges + (size_t)t * 2 * EE + EE;
        atomicAdd(&cnt6[t * NN + dst[e]], 1);
    }
}

// 6 blocks (one per t), 1024 threads: exclusive scan -> rowptr, plus dinv
__global__ void scan6_kernel(const int* __restrict__ cnt6, int* __restrict__ rowptr6,
                             float* __restrict__ dinv6) {
    int t = blockIdx.x;
    const int* cnt = cnt6 + t * NN;
    int* rowptr = rowptr6 + t * (NN + 1);
    float* dinv = dinv6 + t * NN;
    __shared__ int part[1024];
    const int CHUNK = 20;  // 1024*20 >= NN
    int tid = threadIdx.x;
    int base = tid * CHUNK;
    int local[CHUNK];
    int s = 0;
#pragma unroll
    for (int i = 0; i < CHUNK; ++i) {
        int idx = base + i;
        int v = (idx < NN) ? cnt[idx] : 0;
        local[i] = s;
        s += v;
    }
    part[tid] = s;
    __syncthreads();
    for (int off = 1; off < 1024; off <<= 1) {
        int v = part[tid];
        int add = (tid >= off) ? part[tid - off] : 0;
        __syncthreads();
        part[tid] = v + add;
        __syncthreads();
    }
    int ebase = (tid == 0) ? 0 : part[tid - 1];
#pragma unroll
    for (int i = 0; i < CHUNK; ++i) {
        int idx = base + i;
        if (idx < NN) {
            rowptr[idx] = ebase + local[i];
            dinv[idx] = rsqrtf((float)cnt[idx] + 1.0f);
        }
    }
    if (tid == 1023) rowptr[NN] = part[1023];
}

// ---- phase 1: bin edges into 157 coarse buckets (packed dstLocal|src) ----
__global__ void bin6_kernel(const int* __restrict__ edges, int* __restrict__ gcur,
                            int* __restrict__ bucketArr) {
    int t = blockIdx.y;
    __shared__ int hist[NBKT];
    __shared__ int base[NBKT];
    int tid = threadIdx.x;
    for (int i = tid; i < NBKT; i += 256) hist[i] = 0;
    __syncthreads();
    const int* src = edges + (size_t)t * 2 * EE;
    const int* dst = src + EE;
    int e0 = blockIdx.x * EPB;
    int pack[16], loff[16], bkt[16];
    int m = 0;
#pragma unroll
    for (int i = 0; i < 16; ++i) {
        int e = e0 + tid + i * 256;
        if (e < EE) {
            int s = src[e], d = dst[e];
            int b = d >> BKSH;
            bkt[i] = b;
            pack[i] = ((d & 127) << 16) | s;
            loff[i] = atomicAdd(&hist[b], 1);
            m = i + 1;
        }
    }
    __syncthreads();
    for (int i = tid; i < NBKT; i += 256)
        base[i] = atomicAdd(&gcur[t * NBKT + i], hist[i]);
    __syncthreads();
    for (int i = 0; i < m; ++i) {
        int b = bkt[i];
        int pos = base[b] + loff[i];
        if (pos < CAP)
            bucketArr[(size_t)(t * NBKT + b) * CAP + pos] = pack[i];
    }
}

// ---- phase 2: in-LDS regroup of each bucket into per-node CSR segments ---
__global__ void regroup6_kernel(const int* __restrict__ rowptr6, const int* __restrict__ gcur,
                                const int* __restrict__ bucketArr, int* __restrict__ col6) {
    int bk = blockIdx.x, t = blockIdx.y;
    __shared__ int cursor[128];
    __shared__ int lcol[CAP];  // 24KB
    int tid = threadIdx.x;
    const int* rowptr = rowptr6 + t * (NN + 1);
    int nb0 = bk << BKSH;
    int base = rowptr[nb0];
    if (tid < 128) {
        int n = nb0 + tid;
        if (n < NN) cursor[tid] = rowptr[n] - base;
    }
    __syncthreads();
    int ecnt = gcur[t * NBKT + bk];
    if (ecnt > CAP) ecnt = CAP;
    const int* barr = bucketArr + (size_t)(t * NBKT + bk) * CAP;
    for (int e = tid; e < ecnt; e += 256) {
        int w = barr[e];
        int dl = w >> 16, s = w & 0xFFFF;
        int off = atomicAdd(&cursor[dl], 1);
        lcol[off] = s;
    }
    __syncthreads();
    int* colt = col6 + (size_t)t * EE + base;
    for (int e = tid; e < ecnt; e += 256) colt[e] = lcol[e];
}

// ---- GRU weight repack: A[k][jj] = {w_ir,w_iz,w_in,w_hr}, B[k][jj] = {w_hz,w_hn}
__global__ void pack_gru_kernel(const float* __restrict__ wih, const float* __restrict__ whh,
                                float* __restrict__ A, float* __restrict__ B) {
    int idx = blockIdx.x * blockDim.x + threadIdx.x;  // k*64 + jj
    if (idx >= HH * HH) return;
    int k = idx >> 6, jj = idx & 63;
    A[idx * 4 + 0] = wih[jj * HH + k];
    A[idx * 4 + 1] = wih[(64 + jj) * HH + k];
    A[idx * 4 + 2] = wih[(128 + jj) * HH + k];
    A[idx * 4 + 3] = whh[jj * HH + k];
    B[idx * 2 + 0] = whh[(64 + jj) * HH + k];
    B[idx * 2 + 1] = whh[(128 + jj) * HH + k];
}

// ---- y1 for ALL t: y = dinv * (x @ W1), bf16 out ------------------------
__global__ void y1all_kernel(const float* __restrict__ nf, const float* __restrict__ W1,
                             const float* __restrict__ dinv6, unsigned short* __restrict__ Yb) {
    int t = blockIdx.y;
    int gid = blockIdx.x * blockDim.x + threadIdx.x;
    if (gid >= NN * HH) return;
    int node = gid >> 6, hh = gid & 63;
    const float* xr = nf + (size_t)t * NN * CINC + node * CINC;
    float acc = 0.f;
#pragma unroll
    for (int k = 0; k < CINC; ++k) acc = fmaf(xr[k], W1[k * HH + hh], acc);
    Yb[(size_t)t * NN * HH + gid] = f2bf(dinv6[t * NN + node] * acc);
}

// ---- y2: y = dinv * (z @ W2), one wave per RB nodes, bf16 out -----------
__global__ void y2_kernel(const float* __restrict__ z, const float* __restrict__ W2,
                          const float* __restrict__ dinv, unsigned short* __restrict__ y) {
    int nbase = blockIdx.x * RB;
    int lane = threadIdx.x;
    float acc[RB];
#pragma unroll
    for (int r = 0; r < RB; ++r) acc[r] = 0.f;
    for (int k0 = 0; k0 < 16; ++k0) {
        float4 zv[RB];
#pragma unroll
        for (int r = 0; r < RB; ++r)
            zv[r] = ((const float4*)(z + ((size_t)(nbase + r) << 6)))[k0];
#pragma unroll
        for (int u = 0; u < 4; ++u) {
            float w = W2[(k0 * 4 + u) * HH + lane];
#pragma unroll
            for (int r = 0; r < RB; ++r) {
                float zk = (u == 0) ? zv[r].x : (u == 1) ? zv[r].y : (u == 2) ? zv[r].z : zv[r].w;
                acc[r] = fmaf(zk, w, acc[r]);
            }
        }
    }
#pragma unroll
    for (int r = 0; r < RB; ++r)
        y[((size_t)(nbase + r) << 6) + lane] = f2bf(dinv[nbase + r] * acc[r]);
}

// ---- CSR gather (bf16 rows): z[n] = relu(dinv[n]*(sum y[s] + y[n]) + b)
__global__ void gather_kernel(const int* __restrict__ rowptr, const int* __restrict__ col,
                              const float* __restrict__ dinv, const unsigned short* __restrict__ y,
                              const float* __restrict__ b, float* __restrict__ z) {
    int node = (blockIdx.x * blockDim.x + threadIdx.x) >> 6;
    if (node >= NN) return;
    int lane = threadIdx.x & 63;
    int g = lane >> 3, q = lane & 7;
    int ps = rowptr[node], pe = rowptr[node + 1];
    float acc[8];
    if (g == 0) {  // self term
        const uint4 v = *(const uint4*)(y + ((size_t)node << 6) + (q << 3));
        acc[0] = bflo(v.x); acc[1] = bfhi(v.x);
        acc[2] = bflo(v.y); acc[3] = bfhi(v.y);
        acc[4] = bflo(v.z); acc[5] = bfhi(v.z);
        acc[6] = bflo(v.w); acc[7] = bfhi(v.w);
    } else {
#pragma unroll
        for (int j = 0; j < 8; ++j) acc[j] = 0.f;
    }
    for (int p = ps + g; p < pe; p += 8) {
        int c = col[p];
        const uint4 v = *(const uint4*)(y + ((size_t)c << 6) + (q << 3));
        acc[0] += bflo(v.x); acc[1] += bfhi(v.x);
        acc[2] += bflo(v.y); acc[3] += bfhi(v.y);
        acc[4] += bflo(v.z); acc[5] += bfhi(v.z);
        acc[6] += bflo(v.w); acc[7] += bfhi(v.w);
    }
#pragma unroll
    for (int j = 0; j < 8; ++j) {
        acc[j] += __shfl_xor(acc[j], 8);
        acc[j] += __shfl_xor(acc[j], 16);
        acc[j] += __shfl_xor(acc[j], 32);
    }
    if (g == 0) {
        float d = dinv[node];
        const float4 b0 = *(const float4*)(b + (q << 3));
        const float4 b1 = *(const float4*)(b + (q << 3) + 4);
        float4 o0, o1;
        o0.x = fmaf(d, acc[0], b0.x); o0.y = fmaf(d, acc[1], b0.y);
        o0.z = fmaf(d, acc[2], b0.z); o0.w = fmaf(d, acc[3], b0.w);
        o1.x = fmaf(d, acc[4], b1.x); o1.y = fmaf(d, acc[5], b1.y);
        o1.z = fmaf(d, acc[6], b1.z); o1.w = fmaf(d, acc[7], b1.w);
        o0.x = o0.x > 0.f ? o0.x : 0.f; o0.y = o0.y > 0.f ? o0.y : 0.f;
        o0.z = o0.z > 0.f ? o0.z : 0.f; o0.w = o0.w > 0.f ? o0.w : 0.f;
        o1.x = o1.x > 0.f ? o1.x : 0.f; o1.y = o1.y > 0.f ? o1.y : 0.f;
        o1.z = o1.z > 0.f ? o1.z : 0.f; o1.w = o1.w > 0.f ? o1.w : 0.f;
        float* zr = z + ((size_t)node << 6) + (q << 3);
        *(float4*)zr = o0;
        *(float4*)(zr + 4) = o1;
    }
}

// ---- GRU cell: one wave per RB nodes, lane = output feature jj ----------
__global__ void gru_kernel(const float* __restrict__ z, const float* __restrict__ hin,
                           const float* __restrict__ A, const float* __restrict__ B,
                           const float* __restrict__ bih, const float* __restrict__ bhh,
                           float* __restrict__ hout) {
    int nbase = blockIdx.x * RB;
    int lane = threadIdx.x;  // jj
    const float4* A4 = (const float4*)A;
    const float2* B2 = (const float2*)B;
    float ir[RB], iz[RB], in_[RB], hr[RB], hz[RB], hn[RB];
#pragma unroll
    for (int r = 0; r < RB; ++r) { ir[r] = iz[r] = in_[r] = hr[r] = hz[r] = hn[r] = 0.f; }
    for (int k0 = 0; k0 < 16; ++k0) {
        float4 zv[RB], hv[RB];
#pragma unroll
        for (int r = 0; r < RB; ++r) {
            zv[r] = ((const float4*)(z   + ((size_t)(nbase + r) << 6)))[k0];
            hv[r] = ((const float4*)(hin + ((size_t)(nbase + r) << 6)))[k0];
        }
#pragma unroll
        for (int u = 0; u < 4; ++u) {
            int k = k0 * 4 + u;
            float4 a  = A4[(k << 6) + lane];
            float2 b2 = B2[(k << 6) + lane];
#pragma unroll
            for (int r = 0; r < RB; ++r) {
                float zk = (u == 0) ? zv[r].x : (u == 1) ? zv[r].y : (u == 2) ? zv[r].z : zv[r].w;
                float hk = (u == 0) ? hv[r].x : (u == 1) ? hv[r].y : (u == 2) ? hv[r].z : hv[r].w;
                ir[r]  = fmaf(zk, a.x,  ir[r]);
                iz[r]  = fmaf(zk, a.y,  iz[r]);
                in_[r] = fmaf(zk, a.z,  in_[r]);
                hr[r]  = fmaf(hk, a.w,  hr[r]);
                hz[r]  = fmaf(hk, b2.x, hz[r]);
                hn[r]  = fmaf(hk, b2.y, hn[r]);
            }
        }
    }
    float bi0 = bih[lane], bi1 = bih[64 + lane], bi2 = bih[128 + lane];
    float bh0 = bhh[lane], bh1 = bhh[64 + lane], bh2 = bhh[128 + lane];
#pragma unroll
    for (int r = 0; r < RB; ++r) {
        float rr = 1.f / (1.f + expf(-(ir[r] + bi0 + hr[r] + bh0)));
        float zg = 1.f / (1.f + expf(-(iz[r] + bi1 + hz[r] + bh1)));
        float ng = tanhf(in_[r] + bi2 + rr * (hn[r] + bh2));
        float hprev = hin[((size_t)(nbase + r) << 6) + lane];
        hout[((size_t)(nbase + r) << 6) + lane] = (1.f - zg) * ng + zg * hprev;
    }
}

// ---- fused MLP head: out = sigmoid(relu(h@W3+b3)@W4 + b4) ---------------
__global__ void head_kernel(const float* __restrict__ h, const float* __restrict__ W3,
                            const float* __restrict__ b3, const float* __restrict__ W4,
                            const float* __restrict__ b4, float* __restrict__ out) {
    int nbase = blockIdx.x * RB;
    int lane = threadIdx.x;
    float acc[RB];
#pragma unroll
    for (int r = 0; r < RB; ++r) acc[r] = 0.f;
    for (int k0 = 0; k0 < 16; ++k0) {
        float4 hv[RB];
#pragma unroll
        for (int r = 0; r < RB; ++r)
            hv[r] = ((const float4*)(h + ((size_t)(nbase + r) << 6)))[k0];
#pragma unroll
        for (int u = 0; u < 4; ++u) {
            float w = W3[(k0 * 4 + u) * HH + lane];
#pragma unroll
            for (int r = 0; r < RB; ++r) {
                float hk = (u == 0) ? hv[r].x : (u == 1) ? hv[r].y : (u == 2) ? hv[r].z : hv[r].w;
                acc[r] = fmaf(hk, w, acc[r]);
            }
        }
    }
    float bb = b3[lane], w4 = W4[lane], b40 = b4[0];
#pragma unroll
    for (int r = 0; r < RB; ++r) {
        float v = acc[r] + bb;
        v = v > 0.f ? v : 0.f;
        float s = v * w4;
        s += __shfl_xor(s, 32); s += __shfl_xor(s, 16); s += __shfl_xor(s, 8);
        s += __shfl_xor(s, 4);  s += __shfl_xor(s, 2);  s += __shfl_xor(s, 1);
        if (lane == r) out[nbase + r] = 1.f / (1.f + expf(-(s + b40)));
    }
}

extern "C" void kernel_launch(void* const* d_in, const int* in_sizes, int n_in,
                              void* d_out, int out_size, void* d_ws, size_t ws_size,
                              hipStream_t stream) {
    const float* nf    = (const float*)d_in[0];
    const int*   edges = (const int*)  d_in[1];
    const float* W1  = (const float*)d_in[2];
    const float* b1  = (const float*)d_in[3];
    const float* W2  = (const float*)d_in[4];
    const float* b2  = (const float*)d_in[5];
    const float* wih = (const float*)d_in[6];
    const float* whh = (const float*)d_in[7];
    const float* bih = (const float*)d_in[8];
    const float* bhh = (const float*)d_in[9];
    const float* W3  = (const float*)d_in[10];
    const float* b3  = (const float*)d_in[11];
    const float* W4  = (const float*)d_in[12];
    const float* b4  = (const float*)d_in[13];
    float* out = (float*)d_out;

    // workspace layout
    int* wsi      = (int*)d_ws;
    int* cnt6     = wsi;                              // 6*NN
    int* gcur     = cnt6 + 6 * NN;                    // 6*NBKT (zeroed with cnt6)
    int* rowptr6  = gcur + 6 * NBKT;                  // 6*(NN+1)
    int* col6     = rowptr6 + 6 * (NN + 1);           // 6*EE
    int* bucketArr= col6 + (size_t)6 * EE;            // 6*NBKT*CAP
    uintptr_t fbase = ((uintptr_t)(bucketArr + (size_t)6 * NBKT * CAP) + 15) & ~(uintptr_t)15;
    float* packA = (float*)fbase;            // 64*64*4
    float* packB = packA + HH * HH * 4;      // 64*64*2
    float* dinv6 = packB + HH * HH * 2;      // 6*NN
    float* Z     = dinv6 + 6 * NN;           // NN*HH
    float* Hp    = Z + (size_t)NN * HH;      // NN*HH (h ping)
    float* Hq    = Hp + (size_t)NN * HH;     // NN*HH (h pong)
    unsigned short* Yb = (unsigned short*)(Hq + (size_t)NN * HH);  // 6*NN*HH bf16
    unsigned short* Y2 = Yb + (size_t)6 * NN * HH;                 // NN*HH bf16

    const int BS  = 256;
    const int gNH = (NN * HH + BS - 1) / BS;   // 5000
    const int gE  = (EE + BS - 1) / BS;        // 2500
    const int gRB = NN / RB;                   // 2500
    const int gBIN = (EE + EPB - 1) / EPB;     // 157

    hipMemsetAsync(cnt6, 0, (6 * NN + 6 * NBKT) * sizeof(int), stream);
    hipMemsetAsync(Hp, 0, (size_t)NN * HH * sizeof(float), stream);
    pack_gru_kernel<<<(HH * HH + BS - 1) / BS, BS, 0, stream>>>(wih, whh, packA, packB);

    count6_kernel<<<dim3(gE, TT), BS, 0, stream>>>(edges, cnt6);
    scan6_kernel<<<TT, 1024, 0, stream>>>(cnt6, rowptr6, dinv6);
    bin6_kernel<<<dim3(gBIN, TT), BS, 0, stream>>>(edges, gcur, bucketArr);
    regroup6_kernel<<<dim3(NBKT, TT), BS, 0, stream>>>(rowptr6, gcur, bucketArr, col6);
    y1all_kernel<<<dim3(gNH, TT), BS, 0, stream>>>(nf, W1, dinv6, Yb);

    float* hin = Hp;
    float* hout = Hq;
    for (int t = 0; t < TT; ++t) {
        const int* rp = rowptr6 + t * (NN + 1);
        const int* cl = col6 + (size_t)t * EE;
        const float* dv = dinv6 + t * NN;

        gather_kernel<<<gNH, BS, 0, stream>>>(rp, cl, dv, Yb + (size_t)t * NN * HH, b1, Z);
        y2_kernel<<<gRB, 64, 0, stream>>>(Z, W2, dv, Y2);
        gather_kernel<<<gNH, BS, 0, stream>>>(rp, cl, dv, Y2, b2, Z);
        gru_kernel<<<gRB, 64, 0, stream>>>(Z, hin, packA, packB, bih, bhh, hout);
        float* tmp = hin; hin = hout; hout = tmp;
    }

    head_kernel<<<gRB, 64, 0, stream>>>(hin, W3, b3, W4, b4, out);
}

// Round 10
// 478.875 us; speedup vs baseline: 3.4758x; 1.5216x over previous
//
#include <hip/hip_runtime.h>
#include <math.h>

static constexpr int NN   = 20000;
static constexpr int TT   = 6;
static constexpr int EE   = 640000;
static constexpr int CINC = 3;
static constexpr int HH   = 64;
static constexpr int RB   = 8;    // nodes per wave in the dense kernels
static constexpr int BKSH = 7;    // 128 nodes per bucket
static constexpr int NBKT = (NN + (1 << BKSH) - 1) >> BKSH;  // 157
static constexpr int CAP  = 6144; // bucket capacity (expected 4096, +32 sigma)
static constexpr int EPB  = 4096; // edges per workgroup in bin phase

// ---- bf16 helpers (storage = ushort) ------------------------------------
__device__ inline unsigned short f2bf(float f) {
    unsigned u = __float_as_uint(f);
    unsigned r = (u + 0x7FFFu + ((u >> 16) & 1u)) >> 16;  // RTNE
    return (unsigned short)r;
}
__device__ inline float bflo(unsigned u) { return __uint_as_float(u << 16); }
__device__ inline float bfhi(unsigned u) { return __uint_as_float(u & 0xFFFF0000u); }

// ---- phase 1: bin edges into 157 coarse buckets (packed dstLocal|src) ----
__global__ void bin6_kernel(const int* __restrict__ edges, int* __restrict__ gcur,
                            int* __restrict__ bucketArr) {
    int t = blockIdx.y;
    __shared__ int hist[NBKT];
    __shared__ int base[NBKT];
    int tid = threadIdx.x;
    for (int i = tid; i < NBKT; i += 256) hist[i] = 0;
    __syncthreads();
    const int* src = edges + (size_t)t * 2 * EE;
    const int* dst = src + EE;
    int e0 = blockIdx.x * EPB;
    int pack[16], loff[16], bkt[16];
    int m = 0;
#pragma unroll
    for (int i = 0; i < 16; ++i) {
        int e = e0 + tid + i * 256;
        if (e < EE) {
            int s = src[e], d = dst[e];
            int b = d >> BKSH;
            bkt[i] = b;
            pack[i] = ((d & 127) << 16) | s;
            loff[i] = atomicAdd(&hist[b], 1);
            m = i + 1;
        }
    }
    __syncthreads();
    for (int i = tid; i < NBKT; i += 256)
        base[i] = atomicAdd(&gcur[t * NBKT + i], hist[i]);
    __syncthreads();
    for (int i = 0; i < m; ++i) {
        int b = bkt[i];
        int pos = base[b] + loff[i];
        if (pos < CAP)
            bucketArr[(size_t)(t * NBKT + b) * CAP + pos] = pack[i];
    }
}

// ---- per-node degree from buckets: LDS histogram, coalesced write -------
__global__ void bucket_count6_kernel(const int* __restrict__ gcur,
                                     const int* __restrict__ bucketArr,
                                     int* __restrict__ cnt6) {
    int bk = blockIdx.x, t = blockIdx.y;
    __shared__ int hist[128];
    int tid = threadIdx.x;
    if (tid < 128) hist[tid] = 0;
    __syncthreads();
    int ecnt = gcur[t * NBKT + bk];
    if (ecnt > CAP) ecnt = CAP;
    const int* barr = bucketArr + (size_t)(t * NBKT + bk) * CAP;
    for (int e = tid; e < ecnt; e += 256) atomicAdd(&hist[barr[e] >> 16], 1);
    __syncthreads();
    int n = (bk << BKSH) + tid;
    if (tid < 128 && n < NN) cnt6[t * NN + n] = hist[tid];
}

// 6 blocks (one per t), 1024 threads: exclusive scan -> rowptr, plus dinv
__global__ void scan6_kernel(const int* __restrict__ cnt6, int* __restrict__ rowptr6,
                             float* __restrict__ dinv6) {
    int t = blockIdx.x;
    const int* cnt = cnt6 + t * NN;
    int* rowptr = rowptr6 + t * (NN + 1);
    float* dinv = dinv6 + t * NN;
    __shared__ int part[1024];
    const int CHUNK = 20;  // 1024*20 >= NN
    int tid = threadIdx.x;
    int base = tid * CHUNK;
    int local[CHUNK];
    int s = 0;
#pragma unroll
    for (int i = 0; i < CHUNK; ++i) {
        int idx = base + i;
        int v = (idx < NN) ? cnt[idx] : 0;
        local[i] = s;
        s += v;
    }
    part[tid] = s;
    __syncthreads();
    for (int off = 1; off < 1024; off <<= 1) {
        int v = part[tid];
        int add = (tid >= off) ? part[tid - off] : 0;
        __syncthreads();
        part[tid] = v + add;
        __syncthreads();
    }
    int ebase = (tid == 0) ? 0 : part[tid - 1];
#pragma unroll
    for (int i = 0; i < CHUNK; ++i) {
        int idx = base + i;
        if (idx < NN) {
            rowptr[idx] = ebase + local[i];
            dinv[idx] = rsqrtf((float)cnt[idx] + 1.0f);
        }
    }
    if (tid == 1023) rowptr[NN] = part[1023];
}

// ---- phase 2: in-LDS regroup of each bucket into per-node CSR segments ---
__global__ void regroup6_kernel(const int* __restrict__ rowptr6, const int* __restrict__ gcur,
                                const int* __restrict__ bucketArr, int* __restrict__ col6) {
    int bk = blockIdx.x, t = blockIdx.y;
    __shared__ int cursor[128];
    __shared__ int lcol[CAP];  // 24KB
    int tid = threadIdx.x;
    const int* rowptr = rowptr6 + t * (NN + 1);
    int nb0 = bk << BKSH;
    int base = rowptr[nb0];
    if (tid < 128) {
        int n = nb0 + tid;
        if (n < NN) cursor[tid] = rowptr[n] - base;
    }
    __syncthreads();
    int ecnt = gcur[t * NBKT + bk];
    if (ecnt > CAP) ecnt = CAP;
    const int* barr = bucketArr + (size_t)(t * NBKT + bk) * CAP;
    for (int e = tid; e < ecnt; e += 256) {
        int w = barr[e];
        int dl = w >> 16, s = w & 0xFFFF;
        int off = atomicAdd(&cursor[dl], 1);
        lcol[off] = s;
    }
    __syncthreads();
    int* colt = col6 + (size_t)t * EE + base;
    for (int e = tid; e < ecnt; e += 256) colt[e] = lcol[e];
}

// ---- GRU weight repack: A[k][jj] = {w_ir,w_iz,w_in,w_hr}, B[k][jj] = {w_hz,w_hn}
__global__ void pack_gru_kernel(const float* __restrict__ wih, const float* __restrict__ whh,
                                float* __restrict__ A, float* __restrict__ B) {
    int idx = blockIdx.x * blockDim.x + threadIdx.x;  // k*64 + jj
    if (idx >= HH * HH) return;
    int k = idx >> 6, jj = idx & 63;
    A[idx * 4 + 0] = wih[jj * HH + k];
    A[idx * 4 + 1] = wih[(64 + jj) * HH + k];
    A[idx * 4 + 2] = wih[(128 + jj) * HH + k];
    A[idx * 4 + 3] = whh[jj * HH + k];
    B[idx * 2 + 0] = whh[(64 + jj) * HH + k];
    B[idx * 2 + 1] = whh[(128 + jj) * HH + k];
}

// ---- y1 for ALL t: y = dinv * (x @ W1), bf16 out ------------------------
__global__ void y1all_kernel(const float* __restrict__ nf, const float* __restrict__ W1,
                             const float* __restrict__ dinv6, unsigned short* __restrict__ Yb) {
    int t = blockIdx.y;
    int gid = blockIdx.x * blockDim.x + threadIdx.x;
    if (gid >= NN * HH) return;
    int node = gid >> 6, hh = gid & 63;
    const float* xr = nf + (size_t)t * NN * CINC + node * CINC;
    float acc = 0.f;
#pragma unroll
    for (int k = 0; k < CINC; ++k) acc = fmaf(xr[k], W1[k * HH + hh], acc);
    Yb[(size_t)t * NN * HH + gid] = f2bf(dinv6[t * NN + node] * acc);
}

// ---- y2 for ALL t: y = dinv * (z @ W2), one wave per RB nodes, bf16 out --
__global__ void y2all_kernel(const float* __restrict__ Z6, const float* __restrict__ W2,
                             const float* __restrict__ dinv6, unsigned short* __restrict__ Y2all) {
    int t = blockIdx.y;
    const float* z = Z6 + (size_t)t * NN * HH;
    const float* dinv = dinv6 + t * NN;
    unsigned short* y = Y2all + (size_t)t * NN * HH;
    int nbase = blockIdx.x * RB;
    int lane = threadIdx.x;
    float acc[RB];
#pragma unroll
    for (int r = 0; r < RB; ++r) acc[r] = 0.f;
    for (int k0 = 0; k0 < 16; ++k0) {
        float4 zv[RB];
#pragma unroll
        for (int r = 0; r < RB; ++r)
            zv[r] = ((const float4*)(z + ((size_t)(nbase + r) << 6)))[k0];
#pragma unroll
        for (int u = 0; u < 4; ++u) {
            float w = W2[(k0 * 4 + u) * HH + lane];
#pragma unroll
            for (int r = 0; r < RB; ++r) {
                float zk = (u == 0) ? zv[r].x : (u == 1) ? zv[r].y : (u == 2) ? zv[r].z : zv[r].w;
                acc[r] = fmaf(zk, w, acc[r]);
            }
        }
    }
#pragma unroll
    for (int r = 0; r < RB; ++r)
        y[((size_t)(nbase + r) << 6) + lane] = f2bf(dinv[nbase + r] * acc[r]);
}

// ---- CSR gather for ALL t (bf16 rows): z = relu(dinv*(sum y[s] + y[n]) + b)
__global__ void gather6_kernel(const int* __restrict__ rowptr6, const int* __restrict__ col6,
                               const float* __restrict__ dinv6, const unsigned short* __restrict__ ybase,
                               const float* __restrict__ b, float* __restrict__ zbase) {
    int t = blockIdx.y;
    const int* rowptr = rowptr6 + t * (NN + 1);
    const int* col = col6 + (size_t)t * EE;
    const float* dinv = dinv6 + t * NN;
    const unsigned short* y = ybase + (size_t)t * NN * HH;
    float* z = zbase + (size_t)t * NN * HH;

    int node = (blockIdx.x * blockDim.x + threadIdx.x) >> 6;
    if (node >= NN) return;
    int lane = threadIdx.x & 63;
    int g = lane >> 3, q = lane & 7;
    int ps = rowptr[node], pe = rowptr[node + 1];
    float acc[8];
    if (g == 0) {  // self term
        const uint4 v = *(const uint4*)(y + ((size_t)node << 6) + (q << 3));
        acc[0] = bflo(v.x); acc[1] = bfhi(v.x);
        acc[2] = bflo(v.y); acc[3] = bfhi(v.y);
        acc[4] = bflo(v.z); acc[5] = bfhi(v.z);
        acc[6] = bflo(v.w); acc[7] = bfhi(v.w);
    } else {
#pragma unroll
        for (int j = 0; j < 8; ++j) acc[j] = 0.f;
    }
    for (int p = ps + g; p < pe; p += 8) {
        int c = col[p];
        const uint4 v = *(const uint4*)(y + ((size_t)c << 6) + (q << 3));
        acc[0] += bflo(v.x); acc[1] += bfhi(v.x);
        acc[2] += bflo(v.y); acc[3] += bfhi(v.y);
        acc[4] += bflo(v.z); acc[5] += bfhi(v.z);
        acc[6] += bflo(v.w); acc[7] += bfhi(v.w);
    }
#pragma unroll
    for (int j = 0; j < 8; ++j) {
        acc[j] += __shfl_xor(acc[j], 8);
        acc[j] += __shfl_xor(acc[j], 16);
        acc[j] += __shfl_xor(acc[j], 32);
    }
    if (g == 0) {
        float d = dinv[node];
        const float4 b0 = *(const float4*)(b + (q << 3));
        const float4 b1 = *(const float4*)(b + (q << 3) + 4);
        float4 o0, o1;
        o0.x = fmaf(d, acc[0], b0.x); o0.y = fmaf(d, acc[1], b0.y);
        o0.z = fmaf(d, acc[2], b0.z); o0.w = fmaf(d, acc[3], b0.w);
        o1.x = fmaf(d, acc[4], b1.x); o1.y = fmaf(d, acc[5], b1.y);
        o1.z = fmaf(d, acc[6], b1.z); o1.w = fmaf(d, acc[7], b1.w);
        o0.x = o0.x > 0.f ? o0.x : 0.f; o0.y = o0.y > 0.f ? o0.y : 0.f;
        o0.z = o0.z > 0.f ? o0.z : 0.f; o0.w = o0.w > 0.f ? o0.w : 0.f;
        o1.x = o1.x > 0.f ? o1.x : 0.f; o1.y = o1.y > 0.f ? o1.y : 0.f;
        o1.z = o1.z > 0.f ? o1.z : 0.f; o1.w = o1.w > 0.f ? o1.w : 0.f;
        float* zr = z + ((size_t)node << 6) + (q << 3);
        *(float4*)zr = o0;
        *(float4*)(zr + 4) = o1;
    }
}

// ---- GRU cell: one wave per RB nodes, lane = output feature jj ----------
__global__ void gru_kernel(const float* __restrict__ z, const float* __restrict__ hin,
                           const float* __restrict__ A, const float* __restrict__ B,
                           const float* __restrict__ bih, const float* __restrict__ bhh,
                           float* __restrict__ hout) {
    int nbase = blockIdx.x * RB;
    int lane = threadIdx.x;  // jj
    const float4* A4 = (const float4*)A;
    const float2* B2 = (const float2*)B;
    float ir[RB], iz[RB], in_[RB], hr[RB], hz[RB], hn[RB];
#pragma unroll
    for (int r = 0; r < RB; ++r) { ir[r] = iz[r] = in_[r] = hr[r] = hz[r] = hn[r] = 0.f; }
    for (int k0 = 0; k0 < 16; ++k0) {
        float4 zv[RB], hv[RB];
#pragma unroll
        for (int r = 0; r < RB; ++r) {
            zv[r] = ((const float4*)(z   + ((size_t)(nbase + r) << 6)))[k0];
            hv[r] = ((const float4*)(hin + ((size_t)(nbase + r) << 6)))[k0];
        }
#pragma unroll
        for (int u = 0; u < 4; ++u) {
            int k = k0 * 4 + u;
            float4 a  = A4[(k << 6) + lane];
            float2 b2 = B2[(k << 6) + lane];
#pragma unroll
            for (int r = 0; r < RB; ++r) {
                float zk = (u == 0) ? zv[r].x : (u == 1) ? zv[r].y : (u == 2) ? zv[r].z : zv[r].w;
                float hk = (u == 0) ? hv[r].x : (u == 1) ? hv[r].y : (u == 2) ? hv[r].z : hv[r].w;
                ir[r]  = fmaf(zk, a.x,  ir[r]);
                iz[r]  = fmaf(zk, a.y,  iz[r]);
                in_[r] = fmaf(zk, a.z,  in_[r]);
                hr[r]  = fmaf(hk, a.w,  hr[r]);
                hz[r]  = fmaf(hk, b2.x, hz[r]);
                hn[r]  = fmaf(hk, b2.y, hn[r]);
            }
        }
    }
    float bi0 = bih[lane], bi1 = bih[64 + lane], bi2 = bih[128 + lane];
    float bh0 = bhh[lane], bh1 = bhh[64 + lane], bh2 = bhh[128 + lane];
#pragma unroll
    for (int r = 0; r < RB; ++r) {
        float rr = 1.f / (1.f + expf(-(ir[r] + bi0 + hr[r] + bh0)));
        float zg = 1.f / (1.f + expf(-(iz[r] + bi1 + hz[r] + bh1)));
        float ng = tanhf(in_[r] + bi2 + rr * (hn[r] + bh2));
        float hprev = hin[((size_t)(nbase + r) << 6) + lane];
        hout[((size_t)(nbase + r) << 6) + lane] = (1.f - zg) * ng + zg * hprev;
    }
}

// ---- fused MLP head: out = sigmoid(relu(h@W3+b3)@W4 + b4) ---------------
__global__ void head_kernel(const float* __restrict__ h, const float* __restrict__ W3,
                            const float* __restrict__ b3, const float* __restrict__ W4,
                            const float* __restrict__ b4, float* __restrict__ out) {
    int nbase = blockIdx.x * RB;
    int lane = threadIdx.x;
    float acc[RB];
#pragma unroll
    for (int r = 0; r < RB; ++r) acc[r] = 0.f;
    for (int k0 = 0; k0 < 16; ++k0) {
        float4 hv[RB];
#pragma unroll
        for (int r = 0; r < RB; ++r)
            hv[r] = ((const float4*)(h + ((size_t)(nbase + r) << 6)))[k0];
#pragma unroll
        for (int u = 0; u < 4; ++u) {
            float w = W3[(k0 * 4 + u) * HH + lane];
#pragma unroll
            for (int r = 0; r < RB; ++r) {
                float hk = (u == 0) ? hv[r].x : (u == 1) ? hv[r].y : (u == 2) ? hv[r].z : hv[r].w;
                acc[r] = fmaf(hk, w, acc[r]);
            }
        }
    }
    float bb = b3[lane], w4 = W4[lane], b40 = b4[0];
#pragma unroll
    for (int r = 0; r < RB; ++r) {
        float v = acc[r] + bb;
        v = v > 0.f ? v : 0.f;
        float s = v * w4;
        s += __shfl_xor(s, 32); s += __shfl_xor(s, 16); s += __shfl_xor(s, 8);
        s += __shfl_xor(s, 4);  s += __shfl_xor(s, 2);  s += __shfl_xor(s, 1);
        if (lane == r) out[nbase + r] = 1.f / (1.f + expf(-(s + b40)));
    }
}

extern "C" void kernel_launch(void* const* d_in, const int* in_sizes, int n_in,
                              void* d_out, int out_size, void* d_ws, size_t ws_size,
                              hipStream_t stream) {
    const float* nf    = (const float*)d_in[0];
    const int*   edges = (const int*)  d_in[1];
    const float* W1  = (const float*)d_in[2];
    const float* b1  = (const float*)d_in[3];
    const float* W2  = (const float*)d_in[4];
    const float* b2  = (const float*)d_in[5];
    const float* wih = (const float*)d_in[6];
    const float* whh = (const float*)d_in[7];
    const float* bih = (const float*)d_in[8];
    const float* bhh = (const float*)d_in[9];
    const float* W3  = (const float*)d_in[10];
    const float* b3  = (const float*)d_in[11];
    const float* W4  = (const float*)d_in[12];
    const float* b4  = (const float*)d_in[13];
    float* out = (float*)d_out;

    // workspace layout
    int* wsi      = (int*)d_ws;
    int* cnt6     = wsi;                              // 6*NN
    int* gcur     = cnt6 + 6 * NN;                    // 6*NBKT (zeroed)
    int* rowptr6  = gcur + 6 * NBKT;                  // 6*(NN+1)
    int* col6     = rowptr6 + 6 * (NN + 1);           // 6*EE
    int* bucketArr= col6 + (size_t)6 * EE;            // 6*NBKT*CAP
    uintptr_t fbase = ((uintptr_t)(bucketArr + (size_t)6 * NBKT * CAP) + 15) & ~(uintptr_t)15;
    float* packA = (float*)fbase;            // 64*64*4
    float* packB = packA + HH * HH * 4;      // 64*64*2
    float* dinv6 = packB + HH * HH * 2;      // 6*NN
    float* Z6    = dinv6 + 6 * NN;           // 6*NN*HH
    float* Hp    = Z6 + (size_t)6 * NN * HH; // NN*HH (h ping)
    float* Hq    = Hp + (size_t)NN * HH;     // NN*HH (h pong)
    unsigned short* Yb    = (unsigned short*)(Hq + (size_t)NN * HH);  // 6*NN*HH bf16
    unsigned short* Y2all = Yb + (size_t)6 * NN * HH;                 // 6*NN*HH bf16

    const int BS  = 256;
    const int gNH = (NN * HH + BS - 1) / BS;   // 5000
    const int gRB = NN / RB;                   // 2500
    const int gBIN = (EE + EPB - 1) / EPB;     // 157

    hipMemsetAsync(gcur, 0, 6 * NBKT * sizeof(int), stream);
    hipMemsetAsync(Hp, 0, (size_t)NN * HH * sizeof(float), stream);
    pack_gru_kernel<<<(HH * HH + BS - 1) / BS, BS, 0, stream>>>(wih, whh, packA, packB);

    bin6_kernel<<<dim3(gBIN, TT), BS, 0, stream>>>(edges, gcur, bucketArr);
    bucket_count6_kernel<<<dim3(NBKT, TT), BS, 0, stream>>>(gcur, bucketArr, cnt6);
    scan6_kernel<<<TT, 1024, 0, stream>>>(cnt6, rowptr6, dinv6);
    regroup6_kernel<<<dim3(NBKT, TT), BS, 0, stream>>>(rowptr6, gcur, bucketArr, col6);
    y1all_kernel<<<dim3(gNH, TT), BS, 0, stream>>>(nf, W1, dinv6, Yb);

    // GCN layer 1 for all t, then layer-2 dense+gather for all t
    gather6_kernel<<<dim3(gNH, TT), BS, 0, stream>>>(rowptr6, col6, dinv6, Yb, b1, Z6);
    y2all_kernel<<<dim3(gRB, TT), 64, 0, stream>>>(Z6, W2, dinv6, Y2all);
    gather6_kernel<<<dim3(gNH, TT), BS, 0, stream>>>(rowptr6, col6, dinv6, Y2all, b2, Z6);

    // GRU chain (sequential in t)
    float* hin = Hp;
    float* hout = Hq;
    for (int t = 0; t < TT; ++t) {
        gru_kernel<<<gRB, 64, 0, stream>>>(Z6 + (size_t)t * NN * HH, hin, packA, packB,
                                           bih, bhh, hout);
        float* tmp = hin; hin = hout; hout = tmp;
    }

    head_kernel<<<gRB, 64, 0, stream>>>(hin, W3, b3, W4, b4, out);
}

// Round 13
// 471.179 us; speedup vs baseline: 3.5326x; 1.0163x over previous
//
#include <hip/hip_runtime.h>
#include <math.h>

static constexpr int NN   = 20000;
static constexpr int TT   = 6;
static constexpr int EE   = 640000;
static constexpr int CINC = 3;
static constexpr int HH   = 64;
static constexpr int RB   = 8;    // nodes per wave in the dense kernels
static constexpr int BKSH = 7;    // 128 nodes per bucket
static constexpr int NBKT = (NN + (1 << BKSH) - 1) >> BKSH;  // 157
static constexpr int CAP  = 6144; // bucket capacity (expected 4096, +32 sigma)
static constexpr int EPB  = 4096; // edges per workgroup in bin phase

// ---- bf16 helpers (storage = ushort) ------------------------------------
__device__ inline unsigned short f2bf(float f) {
    unsigned u = __float_as_uint(f);
    unsigned r = (u + 0x7FFFu + ((u >> 16) & 1u)) >> 16;  // RTNE
    return (unsigned short)r;
}
__device__ inline float bflo(unsigned u) { return __uint_as_float(u << 16); }
__device__ inline float bfhi(unsigned u) { return __uint_as_float(u & 0xFFFF0000u); }

// ---- phase 1: bin edges into 157 coarse buckets (packed dstLocal|src) ----
__global__ void bin6_kernel(const int* __restrict__ edges, int* __restrict__ gcur,
                            int* __restrict__ bucketArr) {
    int t = blockIdx.y;
    __shared__ int hist[NBKT];
    __shared__ int base[NBKT];
    int tid = threadIdx.x;
    for (int i = tid; i < NBKT; i += 256) hist[i] = 0;
    __syncthreads();
    const int* src = edges + (size_t)t * 2 * EE;
    const int* dst = src + EE;
    int e0 = blockIdx.x * EPB;
    int pack[16], loff[16], bkt[16];
    int m = 0;
#pragma unroll
    for (int i = 0; i < 16; ++i) {
        int e = e0 + tid + i * 256;
        if (e < EE) {
            int s = src[e], d = dst[e];
            int b = d >> BKSH;
            bkt[i] = b;
            pack[i] = ((d & 127) << 16) | s;
            loff[i] = atomicAdd(&hist[b], 1);
            m = i + 1;
        }
    }
    __syncthreads();
    for (int i = tid; i < NBKT; i += 256)
        base[i] = atomicAdd(&gcur[t * NBKT + i], hist[i]);
    __syncthreads();
    for (int i = 0; i < m; ++i) {
        int b = bkt[i];
        int pos = base[b] + loff[i];
        if (pos < CAP)
            bucketArr[(size_t)(t * NBKT + b) * CAP + pos] = pack[i];
    }
}

// ---- per-node degree from buckets: LDS histogram, coalesced write -------
__global__ void bucket_count6_kernel(const int* __restrict__ gcur,
                                     const int* __restrict__ bucketArr,
                                     int* __restrict__ cnt6) {
    int bk = blockIdx.x, t = blockIdx.y;
    __shared__ int hist[128];
    int tid = threadIdx.x;
    if (tid < 128) hist[tid] = 0;
    __syncthreads();
    int ecnt = gcur[t * NBKT + bk];
    if (ecnt > CAP) ecnt = CAP;
    const int* barr = bucketArr + (size_t)(t * NBKT + bk) * CAP;
    for (int e = tid; e < ecnt; e += 256) atomicAdd(&hist[barr[e] >> 16], 1);
    __syncthreads();
    int n = (bk << BKSH) + tid;
    if (tid < 128 && n < NN) cnt6[t * NN + n] = hist[tid];
}

// 6 blocks (one per t), 1024 threads: exclusive scan -> rowptr, plus dinv
__global__ void scan6_kernel(const int* __restrict__ cnt6, int* __restrict__ rowptr6,
                             float* __restrict__ dinv6) {
    int t = blockIdx.x;
    const int* cnt = cnt6 + t * NN;
    int* rowptr = rowptr6 + t * (NN + 1);
    float* dinv = dinv6 + t * NN;
    __shared__ int part[1024];
    const int CHUNK = 20;  // 1024*20 >= NN
    int tid = threadIdx.x;
    int base = tid * CHUNK;
    int local[CHUNK];
    int s = 0;
#pragma unroll
    for (int i = 0; i < CHUNK; ++i) {
        int idx = base + i;
        int v = (idx < NN) ? cnt[idx] : 0;
        local[i] = s;
        s += v;
    }
    part[tid] = s;
    __syncthreads();
    for (int off = 1; off < 1024; off <<= 1) {
        int v = part[tid];
        int add = (tid >= off) ? part[tid - off] : 0;
        __syncthreads();
        part[tid] = v + add;
        __syncthreads();
    }
    int ebase = (tid == 0) ? 0 : part[tid - 1];
#pragma unroll
    for (int i = 0; i < CHUNK; ++i) {
        int idx = base + i;
        if (idx < NN) {
            rowptr[idx] = ebase + local[i];
            dinv[idx] = rsqrtf((float)cnt[idx] + 1.0f);
        }
    }
    if (tid == 1023) rowptr[NN] = part[1023];
}

// ---- phase 2: in-LDS regroup of each bucket into per-node CSR segments ---
__global__ void regroup6_kernel(const int* __restrict__ rowptr6, const int* __restrict__ gcur,
                                const int* __restrict__ bucketArr, int* __restrict__ col6) {
    int bk = blockIdx.x, t = blockIdx.y;
    __shared__ int cursor[128];
    __shared__ int lcol[CAP];  // 24KB
    int tid = threadIdx.x;
    const int* rowptr = rowptr6 + t * (NN + 1);
    int nb0 = bk << BKSH;
    int base = rowptr[nb0];
    if (tid < 128) {
        int n = nb0 + tid;
        if (n < NN) cursor[tid] = rowptr[n] - base;
    }
    __syncthreads();
    int ecnt = gcur[t * NBKT + bk];
    if (ecnt > CAP) ecnt = CAP;
    const int* barr = bucketArr + (size_t)(t * NBKT + bk) * CAP;
    for (int e = tid; e < ecnt; e += 256) {
        int w = barr[e];
        int dl = w >> 16, s = w & 0xFFFF;
        int off = atomicAdd(&cursor[dl], 1);
        lcol[off] = s;
    }
    __syncthreads();
    int* colt = col6 + (size_t)t * EE + base;
    for (int e = tid; e < ecnt; e += 256) colt[e] = lcol[e];
}

// ---- GRU weight repack: A[k][jj] = {w_ir,w_iz,w_in,w_hr}, B[k][jj] = {w_hz,w_hn}
__global__ void pack_gru_kernel(const float* __restrict__ wih, const float* __restrict__ whh,
                                float* __restrict__ A, float* __restrict__ B) {
    int idx = blockIdx.x * blockDim.x + threadIdx.x;  // k*64 + jj
    if (idx >= HH * HH) return;
    int k = idx >> 6, jj = idx & 63;
    A[idx * 4 + 0] = wih[jj * HH + k];
    A[idx * 4 + 1] = wih[(64 + jj) * HH + k];
    A[idx * 4 + 2] = wih[(128 + jj) * HH + k];
    A[idx * 4 + 3] = whh[jj * HH + k];
    B[idx * 2 + 0] = whh[(64 + jj) * HH + k];
    B[idx * 2 + 1] = whh[(128 + jj) * HH + k];
}

// ---- y1 for ALL t: y = dinv * (x @ W1), bf16 out ------------------------
__global__ void y1all_kernel(const float* __restrict__ nf, const float* __restrict__ W1,
                             const float* __restrict__ dinv6, unsigned short* __restrict__ Yb) {
    int t = blockIdx.y;
    int gid = blockIdx.x * blockDim.x + threadIdx.x;
    if (gid >= NN * HH) return;
    int node = gid >> 6, hh = gid & 63;
    const float* xr = nf + (size_t)t * NN * CINC + node * CINC;
    float acc = 0.f;
#pragma unroll
    for (int k = 0; k < CINC; ++k) acc = fmaf(xr[k], W1[k * HH + hh], acc);
    Yb[(size_t)t * NN * HH + gid] = f2bf(dinv6[t * NN + node] * acc);
}

// ---- y2 for ALL t: y = dinv * (z @ W2), bf16 in/out ---------------------
__global__ void y2all_kernel(const unsigned short* __restrict__ Zb6, const float* __restrict__ W2,
                             const float* __restrict__ dinv6, unsigned short* __restrict__ Y2all) {
    int t = blockIdx.y;
    const unsigned short* z = Zb6 + (size_t)t * NN * HH;
    const float* dinv = dinv6 + t * NN;
    unsigned short* y = Y2all + (size_t)t * NN * HH;
    int nbase = blockIdx.x * RB;
    int lane = threadIdx.x;
    float acc[RB];
#pragma unroll
    for (int r = 0; r < RB; ++r) acc[r] = 0.f;
    for (int k0 = 0; k0 < 16; ++k0) {
        uint2 zv[RB];
#pragma unroll
        for (int r = 0; r < RB; ++r)
            zv[r] = *(const uint2*)(z + ((size_t)(nbase + r) << 6) + (k0 << 2));
#pragma unroll
        for (int u = 0; u < 4; ++u) {
            float w = W2[(k0 * 4 + u) * HH + lane];
#pragma unroll
            for (int r = 0; r < RB; ++r) {
                float zk = (u == 0) ? bflo(zv[r].x) : (u == 1) ? bfhi(zv[r].x)
                         : (u == 2) ? bflo(zv[r].y) : bfhi(zv[r].y);
                acc[r] = fmaf(zk, w, acc[r]);
            }
        }
    }
#pragma unroll
    for (int r = 0; r < RB; ++r)
        y[((size_t)(nbase + r) << 6) + lane] = f2bf(dinv[nbase + r] * acc[r]);
}

// ---- CSR gather for ALL t (bf16 rows -> bf16 z): z = relu(dinv*(sum+self)+b)
__global__ void gather6_kernel(const int* __restrict__ rowptr6, const int* __restrict__ col6,
                               const float* __restrict__ dinv6, const unsigned short* __restrict__ ybase,
                               const float* __restrict__ b, unsigned short* __restrict__ zbase) {
    int t = blockIdx.y;
    const int* rowptr = rowptr6 + t * (NN + 1);
    const int* col = col6 + (size_t)t * EE;
    const float* dinv = dinv6 + t * NN;
    const unsigned short* y = ybase + (size_t)t * NN * HH;
    unsigned short* z = zbase + (size_t)t * NN * HH;

    int node = (blockIdx.x * blockDim.x + threadIdx.x) >> 6;
    if (node >= NN) return;
    int lane = threadIdx.x & 63;
    int g = lane >> 3, q = lane & 7;
    int ps = rowptr[node], pe = rowptr[node + 1];
    float acc[8];
    if (g == 0) {  // self term
        const uint4 v = *(const uint4*)(y + ((size_t)node << 6) + (q << 3));
        acc[0] = bflo(v.x); acc[1] = bfhi(v.x);
        acc[2] = bflo(v.y); acc[3] = bfhi(v.y);
        acc[4] = bflo(v.z); acc[5] = bfhi(v.z);
        acc[6] = bflo(v.w); acc[7] = bfhi(v.w);
    } else {
#pragma unroll
        for (int j = 0; j < 8; ++j) acc[j] = 0.f;
    }
    for (int p = ps + g; p < pe; p += 8) {
        int c = col[p];
        const uint4 v = *(const uint4*)(y + ((size_t)c << 6) + (q << 3));
        acc[0] += bflo(v.x); acc[1] += bfhi(v.x);
        acc[2] += bflo(v.y); acc[3] += bfhi(v.y);
        acc[4] += bflo(v.z); acc[5] += bfhi(v.z);
        acc[6] += bflo(v.w); acc[7] += bfhi(v.w);
    }
#pragma unroll
    for (int j = 0; j < 8; ++j) {
        acc[j] += __shfl_xor(acc[j], 8);
        acc[j] += __shfl_xor(acc[j], 16);
        acc[j] += __shfl_xor(acc[j], 32);
    }
    if (g == 0) {
        float d = dinv[node];
        const float4 b0 = *(const float4*)(b + (q << 3));
        const float4 b1 = *(const float4*)(b + (q << 3) + 4);
        float o[8];
        o[0] = fmaf(d, acc[0], b0.x); o[1] = fmaf(d, acc[1], b0.y);
        o[2] = fmaf(d, acc[2], b0.z); o[3] = fmaf(d, acc[3], b0.w);
        o[4] = fmaf(d, acc[4], b1.x); o[5] = fmaf(d, acc[5], b1.y);
        o[6] = fmaf(d, acc[6], b1.z); o[7] = fmaf(d, acc[7], b1.w);
#pragma unroll
        for (int j = 0; j < 8; ++j) o[j] = o[j] > 0.f ? o[j] : 0.f;
        uint4 w;
        w.x = (unsigned)f2bf(o[0]) | ((unsigned)f2bf(o[1]) << 16);
        w.y = (unsigned)f2bf(o[2]) | ((unsigned)f2bf(o[3]) << 16);
        w.z = (unsigned)f2bf(o[4]) | ((unsigned)f2bf(o[5]) << 16);
        w.w = (unsigned)f2bf(o[6]) | ((unsigned)f2bf(o[7]) << 16);
        *(uint4*)(z + ((size_t)node << 6) + (q << 3)) = w;
    }
}

// ---- fused 6-step GRU: h lives in registers across all t ----------------
// one wave (64 threads) per RB nodes; lane = output feature jj
__global__ void gru6_kernel(const unsigned short* __restrict__ Zb6,
                            const float* __restrict__ A, const float* __restrict__ B,
                            const float* __restrict__ bih, const float* __restrict__ bhh,
                            float* __restrict__ hfinal) {
    int nbase = blockIdx.x * RB;
    int lane = threadIdx.x;  // jj
    __shared__ float hs[RB][HH];  // 2 KB
    const float4* A4 = (const float4*)A;
    const float2* B2 = (const float2*)B;
    float h[RB];
#pragma unroll
    for (int r = 0; r < RB; ++r) h[r] = 0.f;
    float bi0 = bih[lane], bi1 = bih[64 + lane], bi2 = bih[128 + lane];
    float bh0 = bhh[lane], bh1 = bhh[64 + lane], bh2 = bhh[128 + lane];

    for (int t = 0; t < TT; ++t) {
        const unsigned short* zb = Zb6 + (size_t)t * NN * HH;
        // stage h into LDS for cross-lane (k-dim) access
#pragma unroll
        for (int r = 0; r < RB; ++r) hs[r][lane] = h[r];
        __syncthreads();
        float ir[RB], iz[RB], in_[RB], hr[RB], hz[RB], hn[RB];
#pragma unroll
        for (int r = 0; r < RB; ++r) { ir[r] = iz[r] = in_[r] = hr[r] = hz[r] = hn[r] = 0.f; }
        for (int k0 = 0; k0 < 16; ++k0) {
            uint2 zv[RB]; float4 hv[RB];
#pragma unroll
            for (int r = 0; r < RB; ++r) {
                zv[r] = *(const uint2*)(zb + ((size_t)(nbase + r) << 6) + (k0 << 2));
                hv[r] = *(const float4*)(&hs[r][k0 << 2]);
            }
#pragma unroll
            for (int u = 0; u < 4; ++u) {
                int k = k0 * 4 + u;
                float4 a  = A4[(k << 6) + lane];
                float2 b2 = B2[(k << 6) + lane];
#pragma unroll
                for (int r = 0; r < RB; ++r) {
                    float zk = (u == 0) ? bflo(zv[r].x) : (u == 1) ? bfhi(zv[r].x)
                             : (u == 2) ? bflo(zv[r].y) : bfhi(zv[r].y);
                    float hk = (u == 0) ? hv[r].x : (u == 1) ? hv[r].y
                             : (u == 2) ? hv[r].z : hv[r].w;
                    ir[r]  = fmaf(zk, a.x,  ir[r]);
                    iz[r]  = fmaf(zk, a.y,  iz[r]);
                    in_[r] = fmaf(zk, a.z,  in_[r]);
                    hr[r]  = fmaf(hk, a.w,  hr[r]);
                    hz[r]  = fmaf(hk, b2.x, hz[r]);
                    hn[r]  = fmaf(hk, b2.y, hn[r]);
                }
            }
        }
        __syncthreads();  // all reads of hs done before next t overwrites
#pragma unroll
        for (int r = 0; r < RB; ++r) {
            float rr = 1.f / (1.f + expf(-(ir[r] + bi0 + hr[r] + bh0)));
            float zg = 1.f / (1.f + expf(-(iz[r] + bi1 + hz[r] + bh1)));
            float ng = tanhf(in_[r] + bi2 + rr * (hn[r] + bh2));
            h[r] = (1.f - zg) * ng + zg * h[r];
        }
    }
#pragma unroll
    for (int r = 0; r < RB; ++r)
        hfinal[((size_t)(nbase + r) << 6) + lane] = h[r];
}

// ---- fused MLP head: out = sigmoid(relu(h@W3+b3)@W4 + b4) ---------------
__global__ void head_kernel(const float* __restrict__ h, const float* __restrict__ W3,
                            const float* __restrict__ b3, const float* __restrict__ W4,
                            const float* __restrict__ b4, float* __restrict__ out) {
    int nbase = blockIdx.x * RB;
    int lane = threadIdx.x;
    float acc[RB];
#pragma unroll
    for (int r = 0; r < RB; ++r) acc[r] = 0.f;
    for (int k0 = 0; k0 < 16; ++k0) {
        float4 hv[RB];
#pragma unroll
        for (int r = 0; r < RB; ++r)
            hv[r] = ((const float4*)(h + ((size_t)(nbase + r) << 6)))[k0];
#pragma unroll
        for (int u = 0; u < 4; ++u) {
            float w = W3[(k0 * 4 + u) * HH + lane];
#pragma unroll
            for (int r = 0; r < RB; ++r) {
                float hk = (u == 0) ? hv[r].x : (u == 1) ? hv[r].y : (u == 2) ? hv[r].z : hv[r].w;
                acc[r] = fmaf(hk, w, acc[r]);
            }
        }
    }
    float bb = b3[lane], w4 = W4[lane], b40 = b4[0];
#pragma unroll
    for (int r = 0; r < RB; ++r) {
        float v = acc[r] + bb;
        v = v > 0.f ? v : 0.f;
        float s = v * w4;
        s += __shfl_xor(s, 32); s += __shfl_xor(s, 16); s += __shfl_xor(s, 8);
        s += __shfl_xor(s, 4);  s += __shfl_xor(s, 2);  s += __shfl_xor(s, 1);
        if (lane == r) out[nbase + r] = 1.f / (1.f + expf(-(s + b40)));
    }
}

extern "C" void kernel_launch(void* const* d_in, const int* in_sizes, int n_in,
                              void* d_out, int out_size, void* d_ws, size_t ws_size,
                              hipStream_t stream) {
    const float* nf    = (const float*)d_in[0];
    const int*   edges = (const int*)  d_in[1];
    const float* W1  = (const float*)d_in[2];
    const float* b1  = (const float*)d_in[3];
    const float* W2  = (const float*)d_in[4];
    const float* b2  = (const float*)d_in[5];
    const float* wih = (const float*)d_in[6];
    const float* whh = (const float*)d_in[7];
    const float* bih = (const float*)d_in[8];
    const float* bhh = (const float*)d_in[9];
    const float* W3  = (const float*)d_in[10];
    const float* b3  = (const float*)d_in[11];
    const float* W4  = (const float*)d_in[12];
    const float* b4  = (const float*)d_in[13];
    float* out = (float*)d_out;

    // workspace layout
    int* wsi      = (int*)d_ws;
    int* cnt6     = wsi;                              // 6*NN
    int* gcur     = cnt6 + 6 * NN;                    // 6*NBKT (zeroed)
    int* rowptr6  = gcur + 6 * NBKT;                  // 6*(NN+1)
    int* col6     = rowptr6 + 6 * (NN + 1);           // 6*EE
    int* bucketArr= col6 + (size_t)6 * EE;            // 6*NBKT*CAP
    uintptr_t fbase = ((uintptr_t)(bucketArr + (size_t)6 * NBKT * CAP) + 15) & ~(uintptr_t)15;
    float* packA = (float*)fbase;            // 64*64*4
    float* packB = packA + HH * HH * 4;      // 64*64*2
    float* dinv6 = packB + HH * HH * 2;      // 6*NN
    float* Hf    = dinv6 + 6 * NN;           // NN*HH (final h, fp32)
    unsigned short* Yb    = (unsigned short*)(Hf + (size_t)NN * HH);  // 6*NN*HH bf16
    unsigned short* Y2all = Yb + (size_t)6 * NN * HH;                 // 6*NN*HH bf16
    unsigned short* Zb1   = Y2all + (size_t)6 * NN * HH;              // 6*NN*HH bf16
    unsigned short* Zb2   = Zb1 + (size_t)6 * NN * HH;                // 6*NN*HH bf16

    const int BS  = 256;
    const int gNH = (NN * HH + BS - 1) / BS;   // 5000
    const int gRB = NN / RB;                   // 2500
    const int gBIN = (EE + EPB - 1) / EPB;     // 157

    hipMemsetAsync(gcur, 0, 6 * NBKT * sizeof(int), stream);
    pack_gru_kernel<<<(HH * HH + BS - 1) / BS, BS, 0, stream>>>(wih, whh, packA, packB);

    bin6_kernel<<<dim3(gBIN, TT), BS, 0, stream>>>(edges, gcur, bucketArr);
    bucket_count6_kernel<<<dim3(NBKT, TT), BS, 0, stream>>>(gcur, bucketArr, cnt6);
    scan6_kernel<<<TT, 1024, 0, stream>>>(cnt6, rowptr6, dinv6);
    regroup6_kernel<<<dim3(NBKT, TT), BS, 0, stream>>>(rowptr6, gcur, bucketArr, col6);
    y1all_kernel<<<dim3(gNH, TT), BS, 0, stream>>>(nf, W1, dinv6, Yb);

    // GCN layer 1 (all t) -> dense (all t) -> GCN layer 2 (all t)
    gather6_kernel<<<dim3(gNH, TT), BS, 0, stream>>>(rowptr6, col6, dinv6, Yb, b1, Zb1);
    y2all_kernel<<<dim3(gRB, TT), 64, 0, stream>>>(Zb1, W2, dinv6, Y2all);
    gather6_kernel<<<dim3(gNH, TT), BS, 0, stream>>>(rowptr6, col6, dinv6, Y2all, b2, Zb2);

    // fused GRU over all 6 timesteps (h in registers)
    gru6_kernel<<<gRB, 64, 0, stream>>>(Zb2, packA, packB, bih, bhh, Hf);

    head_kernel<<<gRB, 64, 0, stream>>>(Hf, W3, b3, W4, b4, out);
}